// Round 7
// baseline (867.632 us; speedup 1.0000x reference)
//
#include <hip/hip_runtime.h>
#include <cstdint>
#include <math.h>

typedef float f32x4 __attribute__((ext_vector_type(4)));
typedef __bf16 bf16x8 __attribute__((ext_vector_type(8)));
typedef unsigned short us4 __attribute__((ext_vector_type(4)));

#define DEV static __device__ __forceinline__

DEV unsigned short f2bf(float f){
  union { __bf16 h; unsigned short u; } cv; cv.h = (__bf16)f; return cv.u;
}
DEV float bf2f(unsigned short u){ return __uint_as_float((unsigned int)u << 16); }

DEV void gload16(const void* g, void* l){
  __builtin_amdgcn_global_load_lds((__attribute__((address_space(1))) void*)g,
                                   (__attribute__((address_space(3))) void*)l, 16, 0, 0);
}

// ---------------- RMSNorm 1 ----------------
__global__ __launch_bounds__(256) void rmsnorm_kernel(const float* __restrict__ x, const float* __restrict__ w,
    unsigned short* __restrict__ ob){
  int t = blockIdx.x, tid = threadIdx.x;
  float4 xv = *(const float4*)(x + (long long)t*1024 + tid*4);
  float ss = xv.x*xv.x + xv.y*xv.y + xv.z*xv.z + xv.w*xv.w;
  for (int m=32;m;m>>=1) ss += __shfl_xor(ss,m);
  __shared__ float lds[4];
  if ((tid&63)==0) lds[tid>>6] = ss;
  __syncthreads();
  float tot = lds[0]+lds[1]+lds[2]+lds[3];
  float inv = rsqrtf(tot*(1.0f/1024.0f) + 1.1920928955078125e-07f);
  float4 wv = *(const float4*)(w + tid*4);
  us4 rb = { f2bf(xv.x*inv*wv.x), f2bf(xv.y*inv*wv.y), f2bf(xv.z*inv*wv.z), f2bf(xv.w*inv*wv.w) };
  *(us4*)&ob[(long long)t*1024 + tid*4] = rb;
}

// ---------------- RMSNorm 2: sum KS partials, write x1 fp32 + h2 bf16 + h2 fp32 ----------------
__global__ __launch_bounds__(256) void rmsnorm2_kernel(const float* __restrict__ xp, int ksn, long long kstride,
    const float* __restrict__ w, float* __restrict__ x1, unsigned short* __restrict__ hb, float* __restrict__ hf){
  int t = blockIdx.x, tid = threadIdx.x;
  long long b = (long long)t*1024 + tid*4;
  float4 xv = {0.f,0.f,0.f,0.f};
  for (int ks=0; ks<ksn; ++ks){
    float4 a = *(const float4*)(xp + ks*kstride + b);
    xv.x+=a.x; xv.y+=a.y; xv.z+=a.z; xv.w+=a.w;
  }
  *(float4*)(x1 + b) = xv;
  float ss = xv.x*xv.x + xv.y*xv.y + xv.z*xv.z + xv.w*xv.w;
  for (int m=32;m;m>>=1) ss += __shfl_xor(ss,m);
  __shared__ float lds[4];
  if ((tid&63)==0) lds[tid>>6] = ss;
  __syncthreads();
  float tot = lds[0]+lds[1]+lds[2]+lds[3];
  float inv = rsqrtf(tot*(1.0f/1024.0f) + 1.1920928955078125e-07f);
  float4 wv = *(const float4*)(w + tid*4);
  float r0 = xv.x*inv*wv.x, r1 = xv.y*inv*wv.y, r2 = xv.z*inv*wv.z, r3 = xv.w*inv*wv.w;
  us4 rb = { f2bf(r0), f2bf(r1), f2bf(r2), f2bf(r3) };
  *(us4*)&hb[b] = rb;
  float4 rf; rf.x=r0; rf.y=r1; rf.z=r2; rf.w=r3;
  *(float4*)(hf + b) = rf;
}

// ---------------- streaming GEMM  C[M,N] = A[M,K](bf16) * B[N,K]^T(fp32) ----------------
// NO LDS, NO BARRIERS. Per wave: independent 64(M)x64(N) tile; block = 4 waves
// stacked along N (64x256 block tile, A-rows shared via L1). Per K-step (32):
// 4 A-frag loads (bf16x8) + 8 B loads (f32x4, cvt->bf16) + 16 MFMA, all from
// global; compiler software-pipelines freely (no sync), waves slip for TLP.
// Bijective chunked XCD remap, by-fastest, for B-panel L2 locality.
// EPI: 1 = fp32 (+resid if ks==0) to Cf+ks*ksoff, 2 = gelu->bf16 Cb rows rbase+lr,
//      3 = fp32 acc*wgt scattered to Cf+ks*ksoff+tok_slot*ldc, 4 = plain bf16 to Cb
template<int EPI, bool GATHER>
__global__ __launch_bounds__(256) void gemm_stream(
    const unsigned short* __restrict__ A, int lda,
    const float* __restrict__ Bw, long long bstride, int ldb,
    int M, int N, int K, int KS, long long ksoff,
    const int* __restrict__ counts, const int* __restrict__ offs,
    const int* __restrict__ tok_list, const float* __restrict__ wgt,
    const float* __restrict__ resid,
    float* __restrict__ Cf, unsigned short* __restrict__ Cb, int ldc)
{
  // bijective chunked XCD remap (m204), x (=by) fastest
  const int gx = gridDim.x, gy = gridDim.y;
  int flat = blockIdx.x + gx*(blockIdx.y + gy*blockIdx.z);
  int nwg = gx*gy*gridDim.z;
  int q = nwg >> 3, r = nwg & 7;
  int xcd = flat & 7, p = flat >> 3;
  int nf = (xcd < r ? xcd*(q+1) : r*(q+1) + (xcd-r)*q) + p;
  const int by = nf % gx;
  int rest = nf / gx;
  const int bx = rest % gy;
  const int z  = rest / gy;

  const int e = z / KS, ks = z - e*KS;
  const int Me = counts ? counts[e] : M;
  if (by * 64 >= Me) return;
  const int rbase = offs ? offs[e] : 0;
  const float* B = Bw + (long long)e * bstride;
  const int kbeg = ks * (K/KS);
  const int nt = (K/KS) >> 5;

  const int lane = threadIdx.x & 63, w = threadIdx.x >> 6;
  const int l15 = lane & 15, l4 = lane >> 4;

  // A row pointers (4 m-frags); per-lane gather for MoE
  const unsigned short* arow[4];
  #pragma unroll
  for (int m=0;m<4;++m){
    int lr = by*64 + m*16 + l15; if (lr >= Me) lr = Me-1;
    int li = rbase + lr;
    int ar = GATHER ? (tok_list[li] >> 1) : li;
    arow[m] = A + (long long)ar*lda + kbeg + l4*8;
  }
  // B row pointers (4 n-frags)
  const float* brow[4];
  #pragma unroll
  for (int n=0;n<4;++n){
    int R = bx*256 + w*64 + n*16 + l15;
    brow[n] = B + (long long)R*ldb + kbeg + l4*8;
  }

  f32x4 acc[4][4] = {};

  #pragma unroll 2
  for (int t = 0; t < nt; ++t){
    const int k0 = t*32;
    bf16x8 af[4];
    #pragma unroll
    for (int m=0;m<4;++m) af[m] = *(const bf16x8*)(arow[m] + k0);
    bf16x8 bfr[4];
    #pragma unroll
    for (int n=0;n<4;++n){
      f32x4 v0 = *(const f32x4*)(brow[n] + k0);
      f32x4 v1 = *(const f32x4*)(brow[n] + k0 + 4);
      bf16x8 tt;
      tt[0]=(__bf16)v0[0]; tt[1]=(__bf16)v0[1]; tt[2]=(__bf16)v0[2]; tt[3]=(__bf16)v0[3];
      tt[4]=(__bf16)v1[0]; tt[5]=(__bf16)v1[1]; tt[6]=(__bf16)v1[2]; tt[7]=(__bf16)v1[3];
      bfr[n] = tt;
    }
    #pragma unroll
    for (int m=0;m<4;++m)
      #pragma unroll
      for (int n=0;n<4;++n)
        acc[m][n] = __builtin_amdgcn_mfma_f32_16x16x32_bf16(af[m], bfr[n], acc[m][n], 0, 0, 0);
  }

  #pragma unroll
  for (int m=0;m<4;++m){
    #pragma unroll
    for (int r2=0;r2<4;++r2){
      int lr = by*64 + m*16 + 4*l4 + r2;
      if (lr >= Me) continue;
      #pragma unroll
      for (int n=0;n<4;++n){
        int col = bx*256 + w*64 + n*16 + l15;
        float v = acc[m][n][r2];
        if constexpr (EPI == 1){
          if (ks == 0) v += resid[(long long)lr*ldc + col];
          Cf[ks*ksoff + (long long)lr*ldc + col] = v;
        } else if constexpr (EPI == 2){
          float g = 0.5f * v * (1.0f + erff(v * 0.70710678118654752f));
          Cb[(long long)(rbase+lr)*ldc + col] = f2bf(g);
        } else if constexpr (EPI == 3){
          int gi = rbase + lr;
          int ts = tok_list[gi];
          Cf[ks*ksoff + (long long)ts*ldc + col] = v * wgt[gi];
        } else {
          Cb[(long long)lr*ldc + col] = f2bf(v);
        }
      }
    }
  }
}

// ---------------- RoPE on bf16 qkv; q,k out bf16 [t][h][64] ----------------
__global__ __launch_bounds__(256) void rope_kernel(const unsigned short* __restrict__ qkvb,
    unsigned short* __restrict__ q, unsigned short* __restrict__ k){
  int t = blockIdx.x, tid = threadIdx.x;
  const unsigned short* row = qkvb + (long long)t*3072;
  #pragma unroll
  for (int u2=0; u2<2; ++u2){
    int pid = tid + u2*256;
    int hh = pid >> 5, j = pid & 31;
    float invf = __expf(-(float)j * 0.28782313662425575f);
    float fr = (float)t * invf;
    float sn, cs;
    __sincosf(fr, &sn, &cs);
    int base = hh*64 + j;
    long long ob_ = (long long)t*1024 + base;
    float a = bf2f(row[base]), b = bf2f(row[base+32]);
    q[ob_]    = f2bf(a*cs - b*sn);
    q[ob_+32] = f2bf(b*cs + a*sn);
    a = bf2f(row[1024+base]); b = bf2f(row[1024+base+32]);
    k[ob_]    = f2bf(a*cs - b*sn);
    k[ob_+32] = f2bf(b*cs + a*sn);
  }
}

// ---------------- causal flash attention ----------------
__global__ __launch_bounds__(256) void attn_kernel(
    const unsigned short* __restrict__ Q,
    const unsigned short* __restrict__ K,
    const unsigned short* __restrict__ V, int ldv,
    unsigned short* __restrict__ O)
{
  const int bx = blockIdx.x, h = blockIdx.y;
  const int q0 = bx*64;
  const int tid = threadIdx.x, lane = tid&63, w = tid>>6;

  __shared__ __align__(16) unsigned short Ks[64*64];
  __shared__ __align__(16) unsigned short Vs[64*64];
  __shared__ __align__(16) unsigned short Ps[4*16*64];
  unsigned short* Pw = Ps + w*1024;

  const int qrow = q0 + w*16 + (lane&15);
  bf16x8 aq[2];
  #pragma unroll
  for (int kk=0;kk<2;++kk)
    aq[kk] = *(const bf16x8*)&Q[(long long)qrow*1024 + h*64 + 32*kk + 8*(lane>>4)];

  f32x4 o[4] = {};
  float Mx[4] = {-INFINITY,-INFINITY,-INFINITY,-INFINITY};
  float Ls[4] = {0.f,0.f,0.f,0.f};

  const int row_g = q0 + w*16 + 4*(lane>>4);
  const int nt = bx + 1;
  for (int it = 0; it < nt; ++it){
    int k0 = it*64;
    #pragma unroll
    for (int i=0;i<2;++i){
      int seg = 4*i + w;
      int row = seg*8 + (lane>>3);
      int cs = (lane&7) ^ (row&7);
      gload16(&K[(long long)(k0+row)*1024 + h*64 + cs*8], &Ks[seg*512]);
      gload16(&V[(long long)(k0+row)*ldv  + h*64 + cs*8], &Vs[seg*512]);
    }
    __syncthreads();
    f32x4 st[4];
    #pragma unroll
    for (int kt=0;kt<4;++kt){
      f32x4 s = {0.f,0.f,0.f,0.f};
      #pragma unroll
      for (int kk=0;kk<2;++kk){
        int R = kt*16 + (lane&15);
        int ch = ((lane>>4)+4*kk) ^ (R&7);
        bf16x8 bk = *(const bf16x8*)&Ks[R*64 + ch*8];
        s = __builtin_amdgcn_mfma_f32_16x16x32_bf16(aq[kk], bk, s, 0,0,0);
      }
      st[kt] = s;
    }
    #pragma unroll
    for (int kt=0;kt<4;++kt){
      int col = k0 + kt*16 + (lane&15);
      #pragma unroll
      for (int r=0;r<4;++r){
        float vv = st[kt][r]*0.125f;
        st[kt][r] = (col <= row_g + r) ? vv : -INFINITY;
      }
    }
    float sf[4];
    #pragma unroll
    for (int r=0;r<4;++r){
      float mx = fmaxf(fmaxf(st[0][r],st[1][r]),fmaxf(st[2][r],st[3][r]));
      mx = fmaxf(mx, __shfl_xor(mx,1));
      mx = fmaxf(mx, __shfl_xor(mx,2));
      mx = fmaxf(mx, __shfl_xor(mx,4));
      mx = fmaxf(mx, __shfl_xor(mx,8));
      float mn = fmaxf(Mx[r], mx);
      float sc = __expf(Mx[r]-mn);
      Mx[r]=mn; sf[r]=sc;
      float ls=0.f;
      #pragma unroll
      for (int kt=0;kt<4;++kt){ float pp = __expf(st[kt][r]-mn); st[kt][r]=pp; ls+=pp; }
      Ls[r] = Ls[r]*sc + ls;
    }
    #pragma unroll
    for (int dt=0;dt<4;++dt)
      #pragma unroll
      for (int r=0;r<4;++r) o[dt][r] *= sf[r];
    #pragma unroll
    for (int kt=0;kt<4;++kt)
      #pragma unroll
      for (int r=0;r<4;++r){
        int prow = 4*(lane>>4)+r, pcol = kt*16+(lane&15);
        int byteoff = (prow*128 + pcol*2) ^ ((prow&7)<<4);
        *(unsigned short*)((char*)Pw + byteoff) = f2bf(st[kt][r]);
      }
    bf16x8 pa[2];
    #pragma unroll
    for (int kk=0;kk<2;++kk){
      int pr = lane&15;
      int ch = ((lane>>4)+4*kk) ^ (pr&7);
      pa[kk] = *(const bf16x8*)&Pw[pr*64 + ch*8];
    }
    #pragma unroll
    for (int dt=0;dt<4;++dt){
      #pragma unroll
      for (int kk=0;kk<2;++kk){
        union { unsigned short u[8]; bf16x8 v; } Ub;
        #pragma unroll
        for (int j=0;j<8;++j){
          int kr = 32*kk + 8*(lane>>4) + j;
          int d = dt*16 + (lane&15);
          int byteoff = (kr*128 + d*2) ^ ((kr&7)<<4);
          Ub.u[j] = *(const unsigned short*)((const char*)Vs + byteoff);
        }
        o[dt] = __builtin_amdgcn_mfma_f32_16x16x32_bf16(pa[kk], Ub.v, o[dt], 0,0,0);
      }
    }
    __syncthreads();
  }
  #pragma unroll
  for (int r=0;r<4;++r){
    float l = Ls[r];
    l += __shfl_xor(l,1); l += __shfl_xor(l,2); l += __shfl_xor(l,4); l += __shfl_xor(l,8);
    Ls[r] = 1.0f / l;
  }
  #pragma unroll
  for (int dt=0;dt<4;++dt)
    #pragma unroll
    for (int r=0;r<4;++r){
      float vv = o[dt][r]*Ls[r];
      int rg = row_g + r;
      O[(long long)rg*1024 + h*64 + dt*16 + (lane&15)] = f2bf(vv);
    }
}

// ---------------- router + top2 ----------------
__global__ __launch_bounds__(256) void router_kernel(const float* __restrict__ h2f, const float* __restrict__ rw,
    float* __restrict__ probs, int* __restrict__ tope, float* __restrict__ topw, int* __restrict__ counts){
  int t = blockIdx.x, tid = threadIdx.x;
  float4 hv = *(const float4*)(h2f + (long long)t*1024 + tid*4);
  float pe[8];
  #pragma unroll
  for (int e2=0;e2<8;++e2){
    float4 wv = *(const float4*)(rw + e2*1024 + tid*4);
    pe[e2] = hv.x*wv.x + hv.y*wv.y + hv.z*wv.z + hv.w*wv.w;
  }
  __shared__ float lds[32];
  #pragma unroll
  for (int e2=0;e2<8;++e2){
    float v = pe[e2];
    for (int m=32;m;m>>=1) v += __shfl_xor(v,m);
    if ((tid&63)==0) lds[(tid>>6)*8+e2] = v;
  }
  __syncthreads();
  if (tid==0){
    float lg[8], pp[8];
    #pragma unroll
    for (int e2=0;e2<8;++e2) lg[e2] = lds[e2]+lds[8+e2]+lds[16+e2]+lds[24+e2];
    float mx = lg[0];
    for (int e2=1;e2<8;++e2) mx = fmaxf(mx, lg[e2]);
    float s = 0.f;
    for (int e2=0;e2<8;++e2){ pp[e2] = __expf(lg[e2]-mx); s += pp[e2]; }
    float inv = 1.0f/s;
    int i0 = 0;
    for (int e2=1;e2<8;++e2) if (pp[e2] > pp[i0]) i0 = e2;
    int i1 = (i0==0)?1:0;
    for (int e2=0;e2<8;++e2) if (e2!=i0 && pp[e2] > pp[i1]) i1 = e2;
    for (int e2=0;e2<8;++e2) probs[t*8+e2] = pp[e2]*inv;
    float p0 = pp[i0], p1 = pp[i1], wsum = p0+p1;
    tope[t*2] = i0; tope[t*2+1] = i1;
    topw[t*2] = p0/wsum; topw[t*2+1] = p1/wsum;
    atomicAdd(&counts[i0],1); atomicAdd(&counts[i1],1);
  }
}

__global__ void init_kernel(int* counts, int* cursor){
  int i = threadIdx.x;
  if (i<8){ counts[i]=0; cursor[i]=0; }
}

__global__ void prefix_kernel(const int* counts, int* offs){
  if (threadIdx.x==0){
    int a=0;
    for (int e2=0;e2<8;++e2){ offs[e2]=a; a+=counts[e2]; }
  }
}

__global__ void scatter_kernel(const int* __restrict__ tope, const float* __restrict__ topw,
    const int* __restrict__ offs, int* __restrict__ cursor, int* __restrict__ tok_list, float* __restrict__ wgt){
  int t = blockIdx.x*blockDim.x + threadIdx.x;
  if (t >= 2048) return;
  #pragma unroll
  for (int s=0;s<2;++s){
    int e2 = tope[t*2+s];
    int pos = atomicAdd(&cursor[e2], 1);
    int i = offs[e2] + pos;
    tok_list[i] = t*2+s;
    wgt[i] = topw[t*2+s];
  }
}

__global__ __launch_bounds__(256) void aux_kernel(const float* __restrict__ probs, float* __restrict__ out){
  int tid = threadIdx.x;
  float pe[8] = {0,0,0,0,0,0,0,0};
  for (int t = tid; t < 2048; t += 256){
    #pragma unroll
    for (int e2=0;e2<8;++e2) pe[e2] += probs[t*8+e2];
  }
  __shared__ float lds[32];
  #pragma unroll
  for (int e2=0;e2<8;++e2){
    float v = pe[e2];
    for (int m=32;m;m>>=1) v += __shfl_xor(v,m);
    if ((tid&63)==0) lds[(tid>>6)*8 + e2] = v;
  }
  __syncthreads();
  if (tid==0){
    float aux = 0.f;
    #pragma unroll
    for (int e2=0;e2<8;++e2){
      float mean = (lds[e2]+lds[8+e2]+lds[16+e2]+lds[24+e2]) * (1.0f/2048.0f);
      aux += mean*mean;
    }
    out[2097152] = 8.0f * aux;
  }
}

__global__ __launch_bounds__(256) void final_kernel(const float* __restrict__ x1, const float* __restrict__ slots,
    int ksn, long long kstride, float* __restrict__ out){
  int t = blockIdx.x, tid = threadIdx.x;
  long long b = (long long)t*1024 + tid*4;
  float4 a = *(const float4*)(x1 + b);
  long long s = (long long)t*2048 + tid*4;
  for (int ks=0; ks<ksn; ++ks){
    float4 s0 = *(const float4*)(slots + ks*kstride + s);
    float4 s1 = *(const float4*)(slots + ks*kstride + s + 1024);
    a.x += s0.x + s1.x; a.y += s0.y + s1.y; a.z += s0.z + s1.z; a.w += s0.w + s1.w;
  }
  *(float4*)(out + b) = a;
}

extern "C" void kernel_launch(void* const* d_in, const int* in_sizes, int n_in,
                              void* d_out, int out_size, void* d_ws, size_t ws_size,
                              hipStream_t stream)
{
  (void)in_sizes; (void)n_in; (void)out_size;
  const float* x    = (const float*)d_in[0];
  const float* qkvw = (const float*)d_in[1];
  const float* outw = (const float*)d_in[2];
  const float* rw   = (const float*)d_in[3];
  const float* w1   = (const float*)d_in[4];
  const float* w2   = (const float*)d_in[5];
  const float* n1w  = (const float*)d_in[6];
  const float* n2w  = (const float*)d_in[7];
  float* out = (float*)d_out;

  char* base = (char*)d_ws;
  const size_t MB = 1ull<<20;
  const bool big = ws_size >= 150*MB;
  const int KSO = big ? 4 : 2;   // out-proj split-K
  const int KSW = big ? 4 : 2;   // w2 split-K

  // region A [0,32MB): pre-MoE bf16 buffers; hid aliases the whole region later
  unsigned short* h_b  = (unsigned short*)(base + 0*MB);
  unsigned short* qb   = (unsigned short*)(base + 4*MB);
  unsigned short* kb   = (unsigned short*)(base + 8*MB);
  unsigned short* ob   = (unsigned short*)(base + 12*MB);
  unsigned short* qkvb = (unsigned short*)(base + 16*MB);   // 12MB
  unsigned short* hid  = (unsigned short*)(base + 0*MB);    // 32MB alias

  float *x1p, *h2f, *slots, *x1;
  unsigned short* h2b;
  char* small_;
  if (big){
    x1p   = (float*)(base + 32*MB);    // KSO x 8MB  -> [32,64)
    h2f   = (float*)(base + 64*MB);    // 8MB        -> [64,72)
    slots = (float*)(base + 72*MB);    // KSW x 16MB -> [72,136)
    x1    = (float*)(base + 136*MB);   // 8MB
    h2b   = (unsigned short*)(base + 144*MB); // 4MB
    small_ = base + 148*MB;
  } else {
    x1p   = (float*)(base + 32*MB);    // 2 x 8MB    -> [32,48)
    h2f   = (float*)(base + 48*MB);    // 8MB        -> [48,56)
    slots = (float*)(base + 32*MB);    // alias, 2x16MB -> [32,64) (x1p/h2f dead by then)
    x1    = (float*)(base + 64*MB);
    h2b   = (unsigned short*)(base + 72*MB);
    small_ = base + 76*MB;
  }
  float* probs = (float*)(small_);
  int*   tope  = (int*)(small_ + 256*1024);
  float* topw  = (float*)(small_ + 512*1024);
  int*   tok_list = (int*)(small_ + 768*1024);
  float* wgt   = (float*)(small_ + 1024*1024);
  int*   counts= (int*)(small_ + 1536*1024);
  int*   offs  = (int*)(small_ + 1536*1024 + 256);
  int*   cursor= (int*)(small_ + 1536*1024 + 512);

  init_kernel<<<1,64,0,stream>>>(counts, cursor);
  rmsnorm_kernel<<<2048,256,0,stream>>>(x, n1w, h_b);
  // qkv: M=2048 N=3072 K=1024 -> grid (by=32, bx=12)
  gemm_stream<4,false><<<dim3(32,12,1),256,0,stream>>>(h_b,1024, qkvw,0,1024, 2048,3072,1024, 1,0,
      nullptr,nullptr,nullptr,nullptr,nullptr, nullptr,qkvb,3072);
  rope_kernel<<<2048,256,0,stream>>>(qkvb, qb, kb);
  attn_kernel<<<dim3(32,16),256,0,stream>>>(qb, kb, qkvb+2048, 3072, ob);
  // out-proj: M=2048 N=1024 K=1024 split KSO -> grid (32,4,KSO)
  gemm_stream<1,false><<<dim3(32,4,KSO),256,0,stream>>>(ob,1024, outw,0,1024, 2048,1024,1024, KSO,(long long)2048*1024,
      nullptr,nullptr,nullptr,nullptr, x, x1p,nullptr,1024);
  rmsnorm2_kernel<<<2048,256,0,stream>>>(x1p, KSO, (long long)2048*1024, n2w, x1, h2b, h2f);
  router_kernel<<<2048,256,0,stream>>>(h2f, rw, probs, tope, topw, counts);
  prefix_kernel<<<1,64,0,stream>>>(counts, offs);
  scatter_kernel<<<8,256,0,stream>>>(tope, topw, offs, cursor, tok_list, wgt);
  // w1: per-expert M<=2048 N=4096 K=1024 -> grid (32,16,8)
  gemm_stream<2,true><<<dim3(32,16,8),256,0,stream>>>(h2b,1024, w1,(long long)4096*1024,1024, 2048,4096,1024, 1,0,
      counts,offs,tok_list,nullptr,nullptr, nullptr,hid,4096);
  // w2: per-expert M<=2048 N=1024 K=4096 split KSW -> grid (32,4,8*KSW)
  gemm_stream<3,false><<<dim3(32,4,8*KSW),256,0,stream>>>(hid,4096, w2,(long long)4096*1024,4096, 2048,1024,4096, KSW,(long long)4096*1024,
      counts,offs,tok_list,wgt,nullptr, slots,nullptr,1024);
  aux_kernel<<<1,256,0,stream>>>(probs, out);
  final_kernel<<<2048,256,0,stream>>>(x1, slots, KSW, (long long)4096*1024, out);
}

// Round 8
// 536.986 us; speedup vs baseline: 1.6157x; 1.6157x over previous
//
#include <hip/hip_runtime.h>
#include <cstdint>
#include <math.h>

typedef float f32x4 __attribute__((ext_vector_type(4)));
typedef __bf16 bf16x8 __attribute__((ext_vector_type(8)));
typedef unsigned short us4 __attribute__((ext_vector_type(4)));
typedef unsigned short us8 __attribute__((ext_vector_type(8)));

#define DEV static __device__ __forceinline__

DEV unsigned short f2bf(float f){
  union { __bf16 h; unsigned short u; } cv; cv.h = (__bf16)f; return cv.u;
}
DEV float bf2f(unsigned short u){ return __uint_as_float((unsigned int)u << 16); }

DEV void gload16(const void* g, void* l){
  __builtin_amdgcn_global_load_lds((__attribute__((address_space(1))) void*)g,
                                   (__attribute__((address_space(3))) void*)l, 16, 0, 0);
}

// ---------------- RMSNorm 1 ----------------
__global__ __launch_bounds__(256) void rmsnorm_kernel(const float* __restrict__ x, const float* __restrict__ w,
    unsigned short* __restrict__ ob){
  int t = blockIdx.x, tid = threadIdx.x;
  float4 xv = *(const float4*)(x + (long long)t*1024 + tid*4);
  float ss = xv.x*xv.x + xv.y*xv.y + xv.z*xv.z + xv.w*xv.w;
  for (int m=32;m;m>>=1) ss += __shfl_xor(ss,m);
  __shared__ float lds[4];
  if ((tid&63)==0) lds[tid>>6] = ss;
  __syncthreads();
  float tot = lds[0]+lds[1]+lds[2]+lds[3];
  float inv = rsqrtf(tot*(1.0f/1024.0f) + 1.1920928955078125e-07f);
  float4 wv = *(const float4*)(w + tid*4);
  us4 rb = { f2bf(xv.x*inv*wv.x), f2bf(xv.y*inv*wv.y), f2bf(xv.z*inv*wv.z), f2bf(xv.w*inv*wv.w) };
  *(us4*)&ob[(long long)t*1024 + tid*4] = rb;
}

// ---------------- RMSNorm 2 ----------------
__global__ __launch_bounds__(256) void rmsnorm2_kernel(const float* __restrict__ xp, int ksn, long long kstride,
    const float* __restrict__ w, float* __restrict__ x1, unsigned short* __restrict__ hb, float* __restrict__ hf){
  int t = blockIdx.x, tid = threadIdx.x;
  long long b = (long long)t*1024 + tid*4;
  float4 xv = {0.f,0.f,0.f,0.f};
  for (int ks=0; ks<ksn; ++ks){
    float4 a = *(const float4*)(xp + ks*kstride + b);
    xv.x+=a.x; xv.y+=a.y; xv.z+=a.z; xv.w+=a.w;
  }
  *(float4*)(x1 + b) = xv;
  float ss = xv.x*xv.x + xv.y*xv.y + xv.z*xv.z + xv.w*xv.w;
  for (int m=32;m;m>>=1) ss += __shfl_xor(ss,m);
  __shared__ float lds[4];
  if ((tid&63)==0) lds[tid>>6] = ss;
  __syncthreads();
  float tot = lds[0]+lds[1]+lds[2]+lds[3];
  float inv = rsqrtf(tot*(1.0f/1024.0f) + 1.1920928955078125e-07f);
  float4 wv = *(const float4*)(w + tid*4);
  float r0 = xv.x*inv*wv.x, r1 = xv.y*inv*wv.y, r2 = xv.z*inv*wv.z, r3 = xv.w*inv*wv.w;
  us4 rb = { f2bf(r0), f2bf(r1), f2bf(r2), f2bf(r3) };
  *(us4*)&hb[b] = rb;
  float4 rf; rf.x=r0; rf.y=r1; rf.z=r2; rf.w=r3;
  *(float4*)(hf + b) = rf;
}

// ---------------- 256x256 4-phase GEMM  C[M,N] = A[M,K](bf16) * B[N,K]^T(fp32) ----------------
// m201-style schedule: 512 thr (8 waves 2Mx4N, wave tile 128x64), BK=64,
// LDS = 2 buf x (A 32KB + B 32KB bf16) = 128KB. A: global_load_lds w/ pre-swizzled
// source; B: reg-staged (issue f32x4 in phase0, cvt+swizzled ds_write in phase3).
// Per phase: {stage ops || 8 ds_read} -> barrier -> setprio(1) 16 MFMA setprio(0) -> barrier.
// Swizzle: phys chunk c = logical ^ (row&7), rows 128B. XCD-bijective remap.
// EPI: 1 = fp32 (+resid if ks==0), 2 = gelu->bf16 rows rbase+lr, 3 = *wgt scatter, 4 = bf16
template<int EPI, bool GATHER>
__global__ __launch_bounds__(512, 1) void gemm256(
    const unsigned short* __restrict__ A, int lda,
    const float* __restrict__ Bw, long long bstride, int ldb,
    int M, int N, int K, int KS, long long ksoff,
    const int* __restrict__ counts, const int* __restrict__ offs,
    const int* __restrict__ tok_list, const float* __restrict__ wgt,
    const float* __restrict__ resid,
    float* __restrict__ Cf, unsigned short* __restrict__ Cb, int ldc)
{
  // bijective chunked XCD remap (m204), by fastest
  const int gx = gridDim.x, gy = gridDim.y;
  int flat = blockIdx.x + gx*(blockIdx.y + gy*blockIdx.z);
  int nwg = gx*gy*gridDim.z;
  int q = nwg >> 3, r = nwg & 7;
  int xcd = flat & 7, p = flat >> 3;
  int nf = (xcd < r ? xcd*(q+1) : r*(q+1) + (xcd-r)*q) + p;
  const int by = nf % gx;
  int rest = nf / gx;
  const int bx = rest % gy;
  const int z  = rest / gy;

  const int e = z / KS, ks = z - e*KS;
  const int Me = counts ? counts[e] : M;
  if (by * 256 >= Me) return;
  const int rbase = offs ? offs[e] : 0;
  const float* B = Bw + (long long)e * bstride;
  const int kn = K / KS;
  const int kbeg = ks * kn;
  const int nt = kn >> 6;

  __shared__ __align__(16) char smem[131072];

  const int tid = threadIdx.x, lane = tid & 63, w = tid >> 6;
  const int wr = w >> 2, wc = w & 3;
  const int l15 = lane & 15, l4 = lane >> 4;

  // A staging sources: 4 gload16/thread/tile; dest linear j*8192 + tid*16
  const unsigned short* asrc[4];
  #pragma unroll
  for (int j=0;j<4;++j){
    int lin = j*8192 + tid*16;
    int R = lin >> 7, c = (lin >> 4) & 7;
    int lr = by*256 + R; if (lr >= Me) lr = Me-1;
    int li = rbase + lr;
    int ar = GATHER ? (tok_list[li] >> 1) : li;
    asrc[j] = A + (long long)ar*lda + kbeg + ((c ^ (R&7))*8);
  }
  // B staging: thread covers 4 units (row = j*64 + tid>>3, pos = tid&7); 2 f32x4 each
  const int brow_ = tid >> 3, bpos = tid & 7;
  const float* bsrc = B + (long long)(bx*256 + brow_)*ldb + kbeg + bpos*8;
  int bdst[4];
  #pragma unroll
  for (int j=0;j<4;++j){
    int row = j*64 + brow_;
    bdst[j] = 32768 + row*128 + ((bpos ^ (row&7)) << 4);
  }

  f32x4 acc[8][4] = {};
  f32x4 rbB[8];

#define ISSUE_A(T) { char* d_ = smem + ((T)&1)*65536; \
    _Pragma("unroll") for (int j=0;j<4;++j) gload16(asrc[j] + (T)*64, d_ + j*8192 + tid*16); }
#define LOAD_B(T) { _Pragma("unroll") for (int j=0;j<4;++j){ \
      const f32x4* p_ = (const f32x4*)(bsrc + (T)*64 + (long long)j*64*ldb); \
      rbB[2*j] = p_[0]; rbB[2*j+1] = p_[1]; } }
#define WRITE_B(T) { char* d_ = smem + ((T)&1)*65536; \
    _Pragma("unroll") for (int j=0;j<4;++j){ \
      union { unsigned short u[8]; us8 v; } U_; \
      _Pragma("unroll") for (int i=0;i<4;++i){ U_.u[i] = f2bf(rbB[2*j][i]); U_.u[4+i] = f2bf(rbB[2*j+1][i]); } \
      *(us8*)(d_ + bdst[j]) = U_.v; } }
#define PHASE(T, KK, MH) { \
    const char* sb_ = smem + ((T)&1)*65536; \
    bf16x8 af_[4], bf_[4]; \
    _Pragma("unroll") for (int mi=0;mi<4;++mi){ \
      int R_ = wr*128 + (MH)*64 + mi*16 + l15; \
      int c_ = (l4 + 4*(KK)) ^ (R_&7); \
      af_[mi] = *(const bf16x8*)(sb_ + R_*128 + c_*16); } \
    _Pragma("unroll") for (int n=0;n<4;++n){ \
      int R_ = wc*64 + n*16 + l15; \
      int c_ = (l4 + 4*(KK)) ^ (R_&7); \
      bf_[n] = *(const bf16x8*)(sb_ + 32768 + R_*128 + c_*16); } \
    __builtin_amdgcn_sched_barrier(0); \
    __builtin_amdgcn_s_barrier(); \
    __builtin_amdgcn_sched_barrier(0); \
    __builtin_amdgcn_s_setprio(1); \
    _Pragma("unroll") for (int mi=0;mi<4;++mi) \
      _Pragma("unroll") for (int n=0;n<4;++n) \
        acc[(MH)*4+mi][n] = __builtin_amdgcn_mfma_f32_16x16x32_bf16(af_[mi], bf_[n], acc[(MH)*4+mi][n], 0,0,0); \
    __builtin_amdgcn_s_setprio(0); \
    __builtin_amdgcn_sched_barrier(0); }

  // prologue: stage tile 0
  ISSUE_A(0); LOAD_B(0);
  asm volatile("s_waitcnt vmcnt(0)" ::: "memory");
  __builtin_amdgcn_sched_barrier(0);
  WRITE_B(0);
  __syncthreads();

  for (int t = 0; t < nt; ++t){
    const bool pf = (t+1 < nt);
    // phase 0: issue all staging for t+1, compute (kk0, mh0)
    if (pf){ ISSUE_A(t+1); LOAD_B(t+1); }
    PHASE(t, 0, 0);
    __builtin_amdgcn_s_barrier();
    __builtin_amdgcn_sched_barrier(0);
    // phase 1
    PHASE(t, 0, 1);
    __builtin_amdgcn_s_barrier();
    __builtin_amdgcn_sched_barrier(0);
    // phase 2
    PHASE(t, 1, 0);
    __builtin_amdgcn_s_barrier();
    __builtin_amdgcn_sched_barrier(0);
    // phase 3: land B regs -> LDS(t+1), compute (kk1, mh1)
    if (pf){
      asm volatile("s_waitcnt vmcnt(0)" ::: "memory");
      __builtin_amdgcn_sched_barrier(0);
      WRITE_B(t+1);
    }
    PHASE(t, 1, 1);
    __syncthreads();   // full drain: ds_writes visible, all reads done before buf reuse
  }

#undef ISSUE_A
#undef LOAD_B
#undef WRITE_B
#undef PHASE

  #pragma unroll
  for (int m=0;m<8;++m){
    #pragma unroll
    for (int r2=0;r2<4;++r2){
      int lr = by*256 + wr*128 + m*16 + 4*l4 + r2;
      if (lr >= Me) continue;
      #pragma unroll
      for (int n=0;n<4;++n){
        int col = bx*256 + wc*64 + n*16 + l15;
        float v = acc[m][n][r2];
        if constexpr (EPI == 1){
          if (ks == 0) v += resid[(long long)lr*ldc + col];
          Cf[ks*ksoff + (long long)lr*ldc + col] = v;
        } else if constexpr (EPI == 2){
          float g = 0.5f * v * (1.0f + erff(v * 0.70710678118654752f));
          Cb[(long long)(rbase+lr)*ldc + col] = f2bf(g);
        } else if constexpr (EPI == 3){
          int gi = rbase + lr;
          int ts = tok_list[gi];
          Cf[ks*ksoff + (long long)ts*ldc + col] = v * wgt[gi];
        } else {
          Cb[(long long)lr*ldc + col] = f2bf(v);
        }
      }
    }
  }
}

// ---------------- RoPE ----------------
__global__ __launch_bounds__(256) void rope_kernel(const unsigned short* __restrict__ qkvb,
    unsigned short* __restrict__ q, unsigned short* __restrict__ k){
  int t = blockIdx.x, tid = threadIdx.x;
  const unsigned short* row = qkvb + (long long)t*3072;
  #pragma unroll
  for (int u2=0; u2<2; ++u2){
    int pid = tid + u2*256;
    int hh = pid >> 5, j = pid & 31;
    float invf = __expf(-(float)j * 0.28782313662425575f);
    float fr = (float)t * invf;
    float sn, cs;
    __sincosf(fr, &sn, &cs);
    int base = hh*64 + j;
    long long ob_ = (long long)t*1024 + base;
    float a = bf2f(row[base]), b = bf2f(row[base+32]);
    q[ob_]    = f2bf(a*cs - b*sn);
    q[ob_+32] = f2bf(b*cs + a*sn);
    a = bf2f(row[1024+base]); b = bf2f(row[1024+base+32]);
    k[ob_]    = f2bf(a*cs - b*sn);
    k[ob_+32] = f2bf(b*cs + a*sn);
  }
}

// ---------------- causal flash attention ----------------
__global__ __launch_bounds__(256) void attn_kernel(
    const unsigned short* __restrict__ Q,
    const unsigned short* __restrict__ K,
    const unsigned short* __restrict__ V, int ldv,
    unsigned short* __restrict__ O)
{
  const int bx = blockIdx.x, h = blockIdx.y;
  const int q0 = bx*64;
  const int tid = threadIdx.x, lane = tid&63, w = tid>>6;

  __shared__ __align__(16) unsigned short Ks[64*64];
  __shared__ __align__(16) unsigned short Vs[64*64];
  __shared__ __align__(16) unsigned short Ps[4*16*64];
  unsigned short* Pw = Ps + w*1024;

  const int qrow = q0 + w*16 + (lane&15);
  bf16x8 aq[2];
  #pragma unroll
  for (int kk=0;kk<2;++kk)
    aq[kk] = *(const bf16x8*)&Q[(long long)qrow*1024 + h*64 + 32*kk + 8*(lane>>4)];

  f32x4 o[4] = {};
  float Mx[4] = {-INFINITY,-INFINITY,-INFINITY,-INFINITY};
  float Ls[4] = {0.f,0.f,0.f,0.f};

  const int row_g = q0 + w*16 + 4*(lane>>4);
  const int nt = bx + 1;
  for (int it = 0; it < nt; ++it){
    int k0 = it*64;
    #pragma unroll
    for (int i=0;i<2;++i){
      int seg = 4*i + w;
      int row = seg*8 + (lane>>3);
      int cs = (lane&7) ^ (row&7);
      gload16(&K[(long long)(k0+row)*1024 + h*64 + cs*8], &Ks[seg*512]);
      gload16(&V[(long long)(k0+row)*ldv  + h*64 + cs*8], &Vs[seg*512]);
    }
    __syncthreads();
    f32x4 st[4];
    #pragma unroll
    for (int kt=0;kt<4;++kt){
      f32x4 s = {0.f,0.f,0.f,0.f};
      #pragma unroll
      for (int kk=0;kk<2;++kk){
        int R = kt*16 + (lane&15);
        int ch = ((lane>>4)+4*kk) ^ (R&7);
        bf16x8 bk = *(const bf16x8*)&Ks[R*64 + ch*8];
        s = __builtin_amdgcn_mfma_f32_16x16x32_bf16(aq[kk], bk, s, 0,0,0);
      }
      st[kt] = s;
    }
    #pragma unroll
    for (int kt=0;kt<4;++kt){
      int col = k0 + kt*16 + (lane&15);
      #pragma unroll
      for (int r=0;r<4;++r){
        float vv = st[kt][r]*0.125f;
        st[kt][r] = (col <= row_g + r) ? vv : -INFINITY;
      }
    }
    float sf[4];
    #pragma unroll
    for (int r=0;r<4;++r){
      float mx = fmaxf(fmaxf(st[0][r],st[1][r]),fmaxf(st[2][r],st[3][r]));
      mx = fmaxf(mx, __shfl_xor(mx,1));
      mx = fmaxf(mx, __shfl_xor(mx,2));
      mx = fmaxf(mx, __shfl_xor(mx,4));
      mx = fmaxf(mx, __shfl_xor(mx,8));
      float mn = fmaxf(Mx[r], mx);
      float sc = __expf(Mx[r]-mn);
      Mx[r]=mn; sf[r]=sc;
      float ls=0.f;
      #pragma unroll
      for (int kt=0;kt<4;++kt){ float pp = __expf(st[kt][r]-mn); st[kt][r]=pp; ls+=pp; }
      Ls[r] = Ls[r]*sc + ls;
    }
    #pragma unroll
    for (int dt=0;dt<4;++dt)
      #pragma unroll
      for (int r=0;r<4;++r) o[dt][r] *= sf[r];
    #pragma unroll
    for (int kt=0;kt<4;++kt)
      #pragma unroll
      for (int r=0;r<4;++r){
        int prow = 4*(lane>>4)+r, pcol = kt*16+(lane&15);
        int byteoff = (prow*128 + pcol*2) ^ ((prow&7)<<4);
        *(unsigned short*)((char*)Pw + byteoff) = f2bf(st[kt][r]);
      }
    bf16x8 pa[2];
    #pragma unroll
    for (int kk=0;kk<2;++kk){
      int pr = lane&15;
      int ch = ((lane>>4)+4*kk) ^ (pr&7);
      pa[kk] = *(const bf16x8*)&Pw[pr*64 + ch*8];
    }
    #pragma unroll
    for (int dt=0;dt<4;++dt){
      #pragma unroll
      for (int kk=0;kk<2;++kk){
        union { unsigned short u[8]; bf16x8 v; } Ub;
        #pragma unroll
        for (int j=0;j<8;++j){
          int kr = 32*kk + 8*(lane>>4) + j;
          int d = dt*16 + (lane&15);
          int byteoff = (kr*128 + d*2) ^ ((kr&7)<<4);
          Ub.u[j] = *(const unsigned short*)((const char*)Vs + byteoff);
        }
        o[dt] = __builtin_amdgcn_mfma_f32_16x16x32_bf16(pa[kk], Ub.v, o[dt], 0,0,0);
      }
    }
    __syncthreads();
  }
  #pragma unroll
  for (int r=0;r<4;++r){
    float l = Ls[r];
    l += __shfl_xor(l,1); l += __shfl_xor(l,2); l += __shfl_xor(l,4); l += __shfl_xor(l,8);
    Ls[r] = 1.0f / l;
  }
  #pragma unroll
  for (int dt=0;dt<4;++dt)
    #pragma unroll
    for (int r=0;r<4;++r){
      float vv = o[dt][r]*Ls[r];
      int rg = row_g + r;
      O[(long long)rg*1024 + h*64 + dt*16 + (lane&15)] = f2bf(vv);
    }
}

// ---------------- router + top2 ----------------
__global__ __launch_bounds__(256) void router_kernel(const float* __restrict__ h2f, const float* __restrict__ rw,
    float* __restrict__ probs, int* __restrict__ tope, float* __restrict__ topw, int* __restrict__ counts){
  int t = blockIdx.x, tid = threadIdx.x;
  float4 hv = *(const float4*)(h2f + (long long)t*1024 + tid*4);
  float pe[8];
  #pragma unroll
  for (int e2=0;e2<8;++e2){
    float4 wv = *(const float4*)(rw + e2*1024 + tid*4);
    pe[e2] = hv.x*wv.x + hv.y*wv.y + hv.z*wv.z + hv.w*wv.w;
  }
  __shared__ float lds[32];
  #pragma unroll
  for (int e2=0;e2<8;++e2){
    float v = pe[e2];
    for (int m=32;m;m>>=1) v += __shfl_xor(v,m);
    if ((tid&63)==0) lds[(tid>>6)*8+e2] = v;
  }
  __syncthreads();
  if (tid==0){
    float lg[8], pp[8];
    #pragma unroll
    for (int e2=0;e2<8;++e2) lg[e2] = lds[e2]+lds[8+e2]+lds[16+e2]+lds[24+e2];
    float mx = lg[0];
    for (int e2=1;e2<8;++e2) mx = fmaxf(mx, lg[e2]);
    float s = 0.f;
    for (int e2=0;e2<8;++e2){ pp[e2] = __expf(lg[e2]-mx); s += pp[e2]; }
    float inv = 1.0f/s;
    int i0 = 0;
    for (int e2=1;e2<8;++e2) if (pp[e2] > pp[i0]) i0 = e2;
    int i1 = (i0==0)?1:0;
    for (int e2=0;e2<8;++e2) if (e2!=i0 && pp[e2] > pp[i1]) i1 = e2;
    for (int e2=0;e2<8;++e2) probs[t*8+e2] = pp[e2]*inv;
    float p0 = pp[i0], p1 = pp[i1], wsum = p0+p1;
    tope[t*2] = i0; tope[t*2+1] = i1;
    topw[t*2] = p0/wsum; topw[t*2+1] = p1/wsum;
    atomicAdd(&counts[i0],1); atomicAdd(&counts[i1],1);
  }
}

__global__ void init_kernel(int* counts, int* cursor){
  int i = threadIdx.x;
  if (i<8){ counts[i]=0; cursor[i]=0; }
}

__global__ void prefix_kernel(const int* counts, int* offs){
  if (threadIdx.x==0){
    int a=0;
    for (int e2=0;e2<8;++e2){ offs[e2]=a; a+=counts[e2]; }
  }
}

__global__ void scatter_kernel(const int* __restrict__ tope, const float* __restrict__ topw,
    const int* __restrict__ offs, int* __restrict__ cursor, int* __restrict__ tok_list, float* __restrict__ wgt){
  int t = blockIdx.x*blockDim.x + threadIdx.x;
  if (t >= 2048) return;
  #pragma unroll
  for (int s=0;s<2;++s){
    int e2 = tope[t*2+s];
    int pos = atomicAdd(&cursor[e2], 1);
    int i = offs[e2] + pos;
    tok_list[i] = t*2+s;
    wgt[i] = topw[t*2+s];
  }
}

__global__ __launch_bounds__(256) void aux_kernel(const float* __restrict__ probs, float* __restrict__ out){
  int tid = threadIdx.x;
  float pe[8] = {0,0,0,0,0,0,0,0};
  for (int t = tid; t < 2048; t += 256){
    #pragma unroll
    for (int e2=0;e2<8;++e2) pe[e2] += probs[t*8+e2];
  }
  __shared__ float lds[32];
  #pragma unroll
  for (int e2=0;e2<8;++e2){
    float v = pe[e2];
    for (int m=32;m;m>>=1) v += __shfl_xor(v,m);
    if ((tid&63)==0) lds[(tid>>6)*8 + e2] = v;
  }
  __syncthreads();
  if (tid==0){
    float aux = 0.f;
    #pragma unroll
    for (int e2=0;e2<8;++e2){
      float mean = (lds[e2]+lds[8+e2]+lds[16+e2]+lds[24+e2]) * (1.0f/2048.0f);
      aux += mean*mean;
    }
    out[2097152] = 8.0f * aux;
  }
}

__global__ __launch_bounds__(256) void final_kernel(const float* __restrict__ x1, const float* __restrict__ slots,
    int ksn, long long kstride, float* __restrict__ out){
  int t = blockIdx.x, tid = threadIdx.x;
  long long b = (long long)t*1024 + tid*4;
  float4 a = *(const float4*)(x1 + b);
  long long s = (long long)t*2048 + tid*4;
  for (int ks=0; ks<ksn; ++ks){
    float4 s0 = *(const float4*)(slots + ks*kstride + s);
    float4 s1 = *(const float4*)(slots + ks*kstride + s + 1024);
    a.x += s0.x + s1.x; a.y += s0.y + s1.y; a.z += s0.z + s1.z; a.w += s0.w + s1.w;
  }
  *(float4*)(out + b) = a;
}

extern "C" void kernel_launch(void* const* d_in, const int* in_sizes, int n_in,
                              void* d_out, int out_size, void* d_ws, size_t ws_size,
                              hipStream_t stream)
{
  (void)in_sizes; (void)n_in; (void)out_size;
  const float* x    = (const float*)d_in[0];
  const float* qkvw = (const float*)d_in[1];
  const float* outw = (const float*)d_in[2];
  const float* rw   = (const float*)d_in[3];
  const float* w1   = (const float*)d_in[4];
  const float* w2   = (const float*)d_in[5];
  const float* n1w  = (const float*)d_in[6];
  const float* n2w  = (const float*)d_in[7];
  float* out = (float*)d_out;

  char* base = (char*)d_ws;
  const size_t MB = 1ull<<20;
  const bool big = ws_size >= 150*MB;
  const int KSO = big ? 4 : 2;   // out-proj split-K
  const int KSW = big ? 4 : 2;   // w2 split-K

  // region A [0,32MB): pre-MoE bf16 buffers; hid aliases the whole region later
  unsigned short* h_b  = (unsigned short*)(base + 0*MB);
  unsigned short* qb   = (unsigned short*)(base + 4*MB);
  unsigned short* kb   = (unsigned short*)(base + 8*MB);
  unsigned short* ob   = (unsigned short*)(base + 12*MB);
  unsigned short* qkvb = (unsigned short*)(base + 16*MB);   // 12MB
  unsigned short* hid  = (unsigned short*)(base + 0*MB);    // 32MB alias

  float *x1p, *h2f, *slots, *x1;
  unsigned short* h2b;
  char* small_;
  if (big){
    x1p   = (float*)(base + 32*MB);    // KSO x 8MB  -> [32,64)
    h2f   = (float*)(base + 64*MB);    // 8MB        -> [64,72)
    slots = (float*)(base + 72*MB);    // KSW x 16MB -> [72,136)
    x1    = (float*)(base + 136*MB);   // 8MB
    h2b   = (unsigned short*)(base + 144*MB); // 4MB
    small_ = base + 148*MB;
  } else {
    x1p   = (float*)(base + 32*MB);    // 2 x 8MB    -> [32,48)
    h2f   = (float*)(base + 48*MB);    // 8MB        -> [48,56)
    slots = (float*)(base + 32*MB);    // alias, 2x16MB -> [32,64) (x1p/h2f dead by then)
    x1    = (float*)(base + 64*MB);
    h2b   = (unsigned short*)(base + 72*MB);
    small_ = base + 76*MB;
  }
  float* probs = (float*)(small_);
  int*   tope  = (int*)(small_ + 256*1024);
  float* topw  = (float*)(small_ + 512*1024);
  int*   tok_list = (int*)(small_ + 768*1024);
  float* wgt   = (float*)(small_ + 1024*1024);
  int*   counts= (int*)(small_ + 1536*1024);
  int*   offs  = (int*)(small_ + 1536*1024 + 256);
  int*   cursor= (int*)(small_ + 1536*1024 + 512);

  init_kernel<<<1,64,0,stream>>>(counts, cursor);
  rmsnorm_kernel<<<2048,256,0,stream>>>(x, n1w, h_b);
  // qkv: M=2048 N=3072 K=1024 -> grid (8,12)
  gemm256<4,false><<<dim3(8,12,1),512,0,stream>>>(h_b,1024, qkvw,0,1024, 2048,3072,1024, 1,0,
      nullptr,nullptr,nullptr,nullptr,nullptr, nullptr,qkvb,3072);
  rope_kernel<<<2048,256,0,stream>>>(qkvb, qb, kb);
  attn_kernel<<<dim3(32,16),256,0,stream>>>(qb, kb, qkvb+2048, 3072, ob);
  // out-proj: M=2048 N=1024 K=1024 split KSO -> grid (8,4,KSO)
  gemm256<1,false><<<dim3(8,4,KSO),512,0,stream>>>(ob,1024, outw,0,1024, 2048,1024,1024, KSO,(long long)2048*1024,
      nullptr,nullptr,nullptr,nullptr, x, x1p,nullptr,1024);
  rmsnorm2_kernel<<<2048,256,0,stream>>>(x1p, KSO, (long long)2048*1024, n2w, x1, h2b, h2f);
  router_kernel<<<2048,256,0,stream>>>(h2f, rw, probs, tope, topw, counts);
  prefix_kernel<<<1,64,0,stream>>>(counts, offs);
  scatter_kernel<<<8,256,0,stream>>>(tope, topw, offs, cursor, tok_list, wgt);
  // w1: per-expert M<=2048 N=4096 K=1024 -> grid (8,16,8)
  gemm256<2,true><<<dim3(8,16,8),512,0,stream>>>(h2b,1024, w1,(long long)4096*1024,1024, 2048,4096,1024, 1,0,
      counts,offs,tok_list,nullptr,nullptr, nullptr,hid,4096);
  // w2: per-expert M<=2048 N=1024 K=4096 split KSW -> grid (8,4,8*KSW)
  gemm256<3,false><<<dim3(8,4,8*KSW),512,0,stream>>>(hid,4096, w2,(long long)4096*1024,4096, 2048,1024,4096, KSW,(long long)4096*1024,
      counts,offs,tok_list,wgt,nullptr, slots,nullptr,1024);
  aux_kernel<<<1,256,0,stream>>>(probs, out);
  final_kernel<<<2048,256,0,stream>>>(x1, slots, KSW, (long long)4096*1024, out);
}

// Round 9
// 501.403 us; speedup vs baseline: 1.7304x; 1.0710x over previous
//
#include <hip/hip_runtime.h>
#include <cstdint>
#include <math.h>

typedef float f32x4 __attribute__((ext_vector_type(4)));
typedef __bf16 bf16x8 __attribute__((ext_vector_type(8)));
typedef unsigned short us4 __attribute__((ext_vector_type(4)));
typedef unsigned short us8 __attribute__((ext_vector_type(8)));

#define DEV static __device__ __forceinline__

DEV unsigned short f2bf(float f){
  union { __bf16 h; unsigned short u; } cv; cv.h = (__bf16)f; return cv.u;
}
DEV float bf2f(unsigned short u){ return __uint_as_float((unsigned int)u << 16); }

DEV void gload16(const void* g, void* l){
  __builtin_amdgcn_global_load_lds((__attribute__((address_space(1))) void*)g,
                                   (__attribute__((address_space(3))) void*)l, 16, 0, 0);
}

// ---------------- RMSNorm 1 ----------------
__global__ __launch_bounds__(256) void rmsnorm_kernel(const float* __restrict__ x, const float* __restrict__ w,
    unsigned short* __restrict__ ob){
  int t = blockIdx.x, tid = threadIdx.x;
  float4 xv = *(const float4*)(x + (long long)t*1024 + tid*4);
  float ss = xv.x*xv.x + xv.y*xv.y + xv.z*xv.z + xv.w*xv.w;
  for (int m=32;m;m>>=1) ss += __shfl_xor(ss,m);
  __shared__ float lds[4];
  if ((tid&63)==0) lds[tid>>6] = ss;
  __syncthreads();
  float tot = lds[0]+lds[1]+lds[2]+lds[3];
  float inv = rsqrtf(tot*(1.0f/1024.0f) + 1.1920928955078125e-07f);
  float4 wv = *(const float4*)(w + tid*4);
  us4 rb = { f2bf(xv.x*inv*wv.x), f2bf(xv.y*inv*wv.y), f2bf(xv.z*inv*wv.z), f2bf(xv.w*inv*wv.w) };
  *(us4*)&ob[(long long)t*1024 + tid*4] = rb;
}

// ---------------- RMSNorm 2 ----------------
__global__ __launch_bounds__(256) void rmsnorm2_kernel(const float* __restrict__ xp, int ksn, long long kstride,
    const float* __restrict__ w, float* __restrict__ x1, unsigned short* __restrict__ hb, float* __restrict__ hf){
  int t = blockIdx.x, tid = threadIdx.x;
  long long b = (long long)t*1024 + tid*4;
  float4 xv = {0.f,0.f,0.f,0.f};
  for (int ks=0; ks<ksn; ++ks){
    float4 a = *(const float4*)(xp + ks*kstride + b);
    xv.x+=a.x; xv.y+=a.y; xv.z+=a.z; xv.w+=a.w;
  }
  *(float4*)(x1 + b) = xv;
  float ss = xv.x*xv.x + xv.y*xv.y + xv.z*xv.z + xv.w*xv.w;
  for (int m=32;m;m>>=1) ss += __shfl_xor(ss,m);
  __shared__ float lds[4];
  if ((tid&63)==0) lds[tid>>6] = ss;
  __syncthreads();
  float tot = lds[0]+lds[1]+lds[2]+lds[3];
  float inv = rsqrtf(tot*(1.0f/1024.0f) + 1.1920928955078125e-07f);
  float4 wv = *(const float4*)(w + tid*4);
  float r0 = xv.x*inv*wv.x, r1 = xv.y*inv*wv.y, r2 = xv.z*inv*wv.z, r3 = xv.w*inv*wv.w;
  us4 rb = { f2bf(r0), f2bf(r1), f2bf(r2), f2bf(r3) };
  *(us4*)&hb[b] = rb;
  float4 rf; rf.x=r0; rf.y=r1; rf.z=r2; rf.w=r3;
  *(float4*)(hf + b) = rf;
}

// ---------------- 3-buffer minimal-sync GEMM  C[M,N] = A[M,K](bf16) * B[N,K]^T(fp32) ----------------
// Tile MTx256, 512 thr (8 waves 2Mx4N), BK=32. THREE K-tile LDS buffers, stage
// distance 2 (tile t stages t+2), ONE raw barrier + counted vmcnt per tile,
// NEVER vmcnt(0) in steady state, no __syncthreads in loop.
// A: global_load_lds, pre-swizzled source. B: fp32 global -> regs (issued for
// t+2 during t) -> cvt bf16 -> swizzled ds_write (for t+1, late in t).
// All LDS rows 64B bf16, swizzle chunk c ^ ((R>>1)&3)  [round-6-proven 0-conflict].
// EPI: 1 = fp32 (+resid if ks==0), 2 = gelu->bf16 rows rbase+lr, 3 = *wgt scatter, 4 = bf16
template<int EPI, bool GATHER, int MT>
__global__ __launch_bounds__(512, 1) void gemm3(
    const unsigned short* __restrict__ A, int lda,
    const float* __restrict__ Bw, long long bstride, int ldb,
    int M, int N, int K, int KS, long long ksoff,
    const int* __restrict__ counts, const int* __restrict__ offs,
    const int* __restrict__ tok_list, const float* __restrict__ wgt,
    const float* __restrict__ resid,
    float* __restrict__ Cf, unsigned short* __restrict__ Cb, int ldc)
{
  constexpr int MF = MT/32;        // m-frags per wave
  constexpr int ATILE = MT*64;     // A tile bytes (MT rows x 64B)
  constexpr int TILEB = ATILE + 16384;  // + B tile (256 rows x 64B)
  constexpr int ALOADS = MT/128;   // gload16 per thread per tile

  // bijective chunked XCD remap (m204), by fastest
  const int gx = gridDim.x, gy = gridDim.y;
  int flat = blockIdx.x + gx*(blockIdx.y + gy*blockIdx.z);
  int nwg = gx*gy*gridDim.z;
  int q = nwg >> 3, r = nwg & 7;
  int xcd = flat & 7, p = flat >> 3;
  int nf = (xcd < r ? xcd*(q+1) : r*(q+1) + (xcd-r)*q) + p;
  const int by = nf % gx;
  int rest = nf / gx;
  const int bx = rest % gy;
  const int z  = rest / gy;

  const int e = z / KS, ks = z - e*KS;
  const int Me = counts ? counts[e] : M;
  if (by * MT >= Me) return;
  const int rbase = offs ? offs[e] : 0;
  const float* B = Bw + (long long)e * bstride;
  const int kn = K / KS;
  const int kbeg = ks * kn;
  const int nt = kn >> 5;          // K-tiles; even, >= 8 for all our shapes

  __shared__ __align__(16) char smem[3*TILEB];

  const int tid = threadIdx.x, lane = tid & 63, w = tid >> 6;
  const int wr = w >> 2, wc = w & 3;
  const int l15 = lane & 15, l4 = lane >> 4;

  // A staging sources (pre-swizzled: chunk cp -> cp ^ ((R>>1)&3); dest linear)
  const unsigned short* asrc[ALOADS];
  #pragma unroll
  for (int j=0;j<ALOADS;++j){
    int L = (j*512 + tid)*16;
    int R = L >> 6, cp = (L >> 4) & 3;
    int lr = by*MT + R; if (lr >= Me) lr = Me-1;
    int li = rbase + lr;
    int ar = GATHER ? (tok_list[li] >> 1) : li;
    asrc[j] = A + (long long)ar*lda + kbeg + ((cp ^ ((R>>1)&3))*8);
  }
  // B reg-stage: per thread 16 floats (2 units of 8), swizzled ds_write dest
  const float* bs[2];
  int bdst[2];
  #pragma unroll
  for (int u=0;u<2;++u){
    int L = (u*512 + tid)*16;
    int R = L >> 6, cp = (L >> 4) & 3;
    bs[u] = B + (long long)(bx*256 + R)*ldb + kbeg + cp*8;
    bdst[u] = ATILE + R*64 + ((cp ^ ((R>>1)&3)) << 4);
  }

  f32x4 acc[MF][4] = {};
  f32x4 ra[4], rb[4];

#define ISSUE_A(T) { char* d_ = smem + ((T)%3)*TILEB; _Pragma("unroll") \
    for (int j=0;j<ALOADS;++j) gload16(asrc[j] + (T)*32, d_ + (j*512+tid)*16); }
#define LOAD_B(T, RB) { _Pragma("unroll") for (int u=0;u<2;++u){ \
    const f32x4* p_ = (const f32x4*)(bs[u] + (T)*32); RB[2*u] = p_[0]; RB[2*u+1] = p_[1]; } }
#define WRITE_B(T, RB) { char* d_ = smem + ((T)%3)*TILEB; _Pragma("unroll") \
    for (int u=0;u<2;++u){ union{unsigned short s[8]; us8 v;} U_; \
      _Pragma("unroll") for (int i=0;i<4;++i){ U_.s[i]=f2bf(RB[2*u][i]); U_.s[4+i]=f2bf(RB[2*u+1][i]); } \
      *(us8*)(d_ + bdst[u]) = U_.v; } }
#define WAIT_VC() { if constexpr (MT==256) asm volatile("s_waitcnt vmcnt(6)" ::: "memory"); \
                    else                   asm volatile("s_waitcnt vmcnt(5)" ::: "memory"); }
#define COMPUTE(T) { const char* ab_ = smem + ((T)%3)*TILEB; \
    bf16x8 bf_[4]; \
    _Pragma("unroll") for (int n=0;n<4;++n){ \
      int R_ = wc*64 + n*16 + l15; int c_ = l4 ^ ((R_>>1)&3); \
      bf_[n] = *(const bf16x8*)(ab_ + ATILE + R_*64 + c_*16); } \
    __builtin_amdgcn_s_setprio(1); \
    _Pragma("unroll") for (int m=0;m<MF;++m){ \
      int R_ = wr*(MT/2) + m*16 + l15; int c_ = l4 ^ ((R_>>1)&3); \
      bf16x8 af_ = *(const bf16x8*)(ab_ + R_*64 + c_*16); \
      _Pragma("unroll") for (int n=0;n<4;++n) \
        acc[m][n] = __builtin_amdgcn_mfma_f32_16x16x32_bf16(af_, bf_[n], acc[m][n], 0,0,0); } \
    __builtin_amdgcn_s_setprio(0); }
#define BODY(T, RHOLD, RFILL) { \
    asm volatile("s_waitcnt lgkmcnt(0)" ::: "memory"); \
    WAIT_VC(); \
    __builtin_amdgcn_sched_barrier(0); \
    __builtin_amdgcn_s_barrier(); \
    __builtin_amdgcn_sched_barrier(0); \
    if ((T)+2 < nt){ ISSUE_A((T)+2); LOAD_B((T)+2, RFILL); } \
    COMPUTE(T); \
    if ((T)+1 < nt){ \
      __builtin_amdgcn_sched_barrier(0); \
      if ((T)+2 < nt){ WAIT_VC(); } \
      else { asm volatile("s_waitcnt vmcnt(0)" ::: "memory"); } \
      __builtin_amdgcn_sched_barrier(0); \
      WRITE_B((T)+1, RHOLD); \
    } }

  // prologue: stage tiles 0 and 1
  ISSUE_A(0); LOAD_B(0, ra);
  ISSUE_A(1); LOAD_B(1, rb);
  WAIT_VC();                       // tile-0 loads landed (tile-1's may be in flight)
  __builtin_amdgcn_sched_barrier(0);
  WRITE_B(0, ra);

  for (int t = 0; t < nt; t += 2){
    BODY(t, rb, ra);               // rb holds B(t+1); fill ra with B(t+2)
    BODY(t+1, ra, rb);             // ra holds B(t+2); fill rb with B(t+3)
  }

#undef ISSUE_A
#undef LOAD_B
#undef WRITE_B
#undef WAIT_VC
#undef COMPUTE
#undef BODY

  #pragma unroll
  for (int m=0;m<MF;++m){
    #pragma unroll
    for (int r2=0;r2<4;++r2){
      int lr = by*MT + wr*(MT/2) + m*16 + 4*l4 + r2;
      if (lr >= Me) continue;
      #pragma unroll
      for (int n=0;n<4;++n){
        int col = bx*256 + wc*64 + n*16 + l15;
        float v = acc[m][n][r2];
        if constexpr (EPI == 1){
          if (ks == 0) v += resid[(long long)lr*ldc + col];
          Cf[ks*ksoff + (long long)lr*ldc + col] = v;
        } else if constexpr (EPI == 2){
          float g = 0.5f * v * (1.0f + erff(v * 0.70710678118654752f));
          Cb[(long long)(rbase+lr)*ldc + col] = f2bf(g);
        } else if constexpr (EPI == 3){
          int gi = rbase + lr;
          int ts = tok_list[gi];
          Cf[ks*ksoff + (long long)ts*ldc + col] = v * wgt[gi];
        } else {
          Cb[(long long)lr*ldc + col] = f2bf(v);
        }
      }
    }
  }
}

// ---------------- RoPE ----------------
__global__ __launch_bounds__(256) void rope_kernel(const unsigned short* __restrict__ qkvb,
    unsigned short* __restrict__ q, unsigned short* __restrict__ k){
  int t = blockIdx.x, tid = threadIdx.x;
  const unsigned short* row = qkvb + (long long)t*3072;
  #pragma unroll
  for (int u2=0; u2<2; ++u2){
    int pid = tid + u2*256;
    int hh = pid >> 5, j = pid & 31;
    float invf = __expf(-(float)j * 0.28782313662425575f);
    float fr = (float)t * invf;
    float sn, cs;
    __sincosf(fr, &sn, &cs);
    int base = hh*64 + j;
    long long ob_ = (long long)t*1024 + base;
    float a = bf2f(row[base]), b = bf2f(row[base+32]);
    q[ob_]    = f2bf(a*cs - b*sn);
    q[ob_+32] = f2bf(b*cs + a*sn);
    a = bf2f(row[1024+base]); b = bf2f(row[1024+base+32]);
    k[ob_]    = f2bf(a*cs - b*sn);
    k[ob_+32] = f2bf(b*cs + a*sn);
  }
}

// ---------------- causal flash attention ----------------
__global__ __launch_bounds__(256) void attn_kernel(
    const unsigned short* __restrict__ Q,
    const unsigned short* __restrict__ K,
    const unsigned short* __restrict__ V, int ldv,
    unsigned short* __restrict__ O)
{
  const int bx = blockIdx.x, h = blockIdx.y;
  const int q0 = bx*64;
  const int tid = threadIdx.x, lane = tid&63, w = tid>>6;

  __shared__ __align__(16) unsigned short Ks[64*64];
  __shared__ __align__(16) unsigned short Vs[64*64];
  __shared__ __align__(16) unsigned short Ps[4*16*64];
  unsigned short* Pw = Ps + w*1024;

  const int qrow = q0 + w*16 + (lane&15);
  bf16x8 aq[2];
  #pragma unroll
  for (int kk=0;kk<2;++kk)
    aq[kk] = *(const bf16x8*)&Q[(long long)qrow*1024 + h*64 + 32*kk + 8*(lane>>4)];

  f32x4 o[4] = {};
  float Mx[4] = {-INFINITY,-INFINITY,-INFINITY,-INFINITY};
  float Ls[4] = {0.f,0.f,0.f,0.f};

  const int row_g = q0 + w*16 + 4*(lane>>4);
  const int nt = bx + 1;
  for (int it = 0; it < nt; ++it){
    int k0 = it*64;
    #pragma unroll
    for (int i=0;i<2;++i){
      int seg = 4*i + w;
      int row = seg*8 + (lane>>3);
      int cs = (lane&7) ^ (row&7);
      gload16(&K[(long long)(k0+row)*1024 + h*64 + cs*8], &Ks[seg*512]);
      gload16(&V[(long long)(k0+row)*ldv  + h*64 + cs*8], &Vs[seg*512]);
    }
    __syncthreads();
    f32x4 st[4];
    #pragma unroll
    for (int kt=0;kt<4;++kt){
      f32x4 s = {0.f,0.f,0.f,0.f};
      #pragma unroll
      for (int kk=0;kk<2;++kk){
        int R = kt*16 + (lane&15);
        int ch = ((lane>>4)+4*kk) ^ (R&7);
        bf16x8 bk = *(const bf16x8*)&Ks[R*64 + ch*8];
        s = __builtin_amdgcn_mfma_f32_16x16x32_bf16(aq[kk], bk, s, 0,0,0);
      }
      st[kt] = s;
    }
    #pragma unroll
    for (int kt=0;kt<4;++kt){
      int col = k0 + kt*16 + (lane&15);
      #pragma unroll
      for (int r=0;r<4;++r){
        float vv = st[kt][r]*0.125f;
        st[kt][r] = (col <= row_g + r) ? vv : -INFINITY;
      }
    }
    float sf[4];
    #pragma unroll
    for (int r=0;r<4;++r){
      float mx = fmaxf(fmaxf(st[0][r],st[1][r]),fmaxf(st[2][r],st[3][r]));
      mx = fmaxf(mx, __shfl_xor(mx,1));
      mx = fmaxf(mx, __shfl_xor(mx,2));
      mx = fmaxf(mx, __shfl_xor(mx,4));
      mx = fmaxf(mx, __shfl_xor(mx,8));
      float mn = fmaxf(Mx[r], mx);
      float sc = __expf(Mx[r]-mn);
      Mx[r]=mn; sf[r]=sc;
      float ls=0.f;
      #pragma unroll
      for (int kt=0;kt<4;++kt){ float pp = __expf(st[kt][r]-mn); st[kt][r]=pp; ls+=pp; }
      Ls[r] = Ls[r]*sc + ls;
    }
    #pragma unroll
    for (int dt=0;dt<4;++dt)
      #pragma unroll
      for (int r=0;r<4;++r) o[dt][r] *= sf[r];
    #pragma unroll
    for (int kt=0;kt<4;++kt)
      #pragma unroll
      for (int r=0;r<4;++r){
        int prow = 4*(lane>>4)+r, pcol = kt*16+(lane&15);
        int byteoff = (prow*128 + pcol*2) ^ ((prow&7)<<4);
        *(unsigned short*)((char*)Pw + byteoff) = f2bf(st[kt][r]);
      }
    bf16x8 pa[2];
    #pragma unroll
    for (int kk=0;kk<2;++kk){
      int pr = lane&15;
      int ch = ((lane>>4)+4*kk) ^ (pr&7);
      pa[kk] = *(const bf16x8*)&Pw[pr*64 + ch*8];
    }
    #pragma unroll
    for (int dt=0;dt<4;++dt){
      #pragma unroll
      for (int kk=0;kk<2;++kk){
        union { unsigned short u[8]; bf16x8 v; } Ub;
        #pragma unroll
        for (int j=0;j<8;++j){
          int kr = 32*kk + 8*(lane>>4) + j;
          int d = dt*16 + (lane&15);
          int byteoff = (kr*128 + d*2) ^ ((kr&7)<<4);
          Ub.u[j] = *(const unsigned short*)((const char*)Vs + byteoff);
        }
        o[dt] = __builtin_amdgcn_mfma_f32_16x16x32_bf16(pa[kk], Ub.v, o[dt], 0,0,0);
      }
    }
    __syncthreads();
  }
  #pragma unroll
  for (int r=0;r<4;++r){
    float l = Ls[r];
    l += __shfl_xor(l,1); l += __shfl_xor(l,2); l += __shfl_xor(l,4); l += __shfl_xor(l,8);
    Ls[r] = 1.0f / l;
  }
  #pragma unroll
  for (int dt=0;dt<4;++dt)
    #pragma unroll
    for (int r=0;r<4;++r){
      float vv = o[dt][r]*Ls[r];
      int rg = row_g + r;
      O[(long long)rg*1024 + h*64 + dt*16 + (lane&15)] = f2bf(vv);
    }
}

// ---------------- router + top2 ----------------
__global__ __launch_bounds__(256) void router_kernel(const float* __restrict__ h2f, const float* __restrict__ rw,
    float* __restrict__ probs, int* __restrict__ tope, float* __restrict__ topw, int* __restrict__ counts){
  int t = blockIdx.x, tid = threadIdx.x;
  float4 hv = *(const float4*)(h2f + (long long)t*1024 + tid*4);
  float pe[8];
  #pragma unroll
  for (int e2=0;e2<8;++e2){
    float4 wv = *(const float4*)(rw + e2*1024 + tid*4);
    pe[e2] = hv.x*wv.x + hv.y*wv.y + hv.z*wv.z + hv.w*wv.w;
  }
  __shared__ float lds[32];
  #pragma unroll
  for (int e2=0;e2<8;++e2){
    float v = pe[e2];
    for (int m=32;m;m>>=1) v += __shfl_xor(v,m);
    if ((tid&63)==0) lds[(tid>>6)*8+e2] = v;
  }
  __syncthreads();
  if (tid==0){
    float lg[8], pp[8];
    #pragma unroll
    for (int e2=0;e2<8;++e2) lg[e2] = lds[e2]+lds[8+e2]+lds[16+e2]+lds[24+e2];
    float mx = lg[0];
    for (int e2=1;e2<8;++e2) mx = fmaxf(mx, lg[e2]);
    float s = 0.f;
    for (int e2=0;e2<8;++e2){ pp[e2] = __expf(lg[e2]-mx); s += pp[e2]; }
    float inv = 1.0f/s;
    int i0 = 0;
    for (int e2=1;e2<8;++e2) if (pp[e2] > pp[i0]) i0 = e2;
    int i1 = (i0==0)?1:0;
    for (int e2=0;e2<8;++e2) if (e2!=i0 && pp[e2] > pp[i1]) i1 = e2;
    for (int e2=0;e2<8;++e2) probs[t*8+e2] = pp[e2]*inv;
    float p0 = pp[i0], p1 = pp[i1], wsum = p0+p1;
    tope[t*2] = i0; tope[t*2+1] = i1;
    topw[t*2] = p0/wsum; topw[t*2+1] = p1/wsum;
    atomicAdd(&counts[i0],1); atomicAdd(&counts[i1],1);
  }
}

__global__ void init_kernel(int* counts, int* cursor){
  int i = threadIdx.x;
  if (i<8){ counts[i]=0; cursor[i]=0; }
}

__global__ void prefix_kernel(const int* counts, int* offs){
  if (threadIdx.x==0){
    int a=0;
    for (int e2=0;e2<8;++e2){ offs[e2]=a; a+=counts[e2]; }
  }
}

__global__ void scatter_kernel(const int* __restrict__ tope, const float* __restrict__ topw,
    const int* __restrict__ offs, int* __restrict__ cursor, int* __restrict__ tok_list, float* __restrict__ wgt){
  int t = blockIdx.x*blockDim.x + threadIdx.x;
  if (t >= 2048) return;
  #pragma unroll
  for (int s=0;s<2;++s){
    int e2 = tope[t*2+s];
    int pos = atomicAdd(&cursor[e2], 1);
    int i = offs[e2] + pos;
    tok_list[i] = t*2+s;
    wgt[i] = topw[t*2+s];
  }
}

__global__ __launch_bounds__(256) void aux_kernel(const float* __restrict__ probs, float* __restrict__ out){
  int tid = threadIdx.x;
  float pe[8] = {0,0,0,0,0,0,0,0};
  for (int t = tid; t < 2048; t += 256){
    #pragma unroll
    for (int e2=0;e2<8;++e2) pe[e2] += probs[t*8+e2];
  }
  __shared__ float lds[32];
  #pragma unroll
  for (int e2=0;e2<8;++e2){
    float v = pe[e2];
    for (int m=32;m;m>>=1) v += __shfl_xor(v,m);
    if ((tid&63)==0) lds[(tid>>6)*8 + e2] = v;
  }
  __syncthreads();
  if (tid==0){
    float aux = 0.f;
    #pragma unroll
    for (int e2=0;e2<8;++e2){
      float mean = (lds[e2]+lds[8+e2]+lds[16+e2]+lds[24+e2]) * (1.0f/2048.0f);
      aux += mean*mean;
    }
    out[2097152] = 8.0f * aux;
  }
}

__global__ __launch_bounds__(256) void final_kernel(const float* __restrict__ x1, const float* __restrict__ slots,
    int ksn, long long kstride, float* __restrict__ out){
  int t = blockIdx.x, tid = threadIdx.x;
  long long b = (long long)t*1024 + tid*4;
  float4 a = *(const float4*)(x1 + b);
  long long s = (long long)t*2048 + tid*4;
  for (int ks=0; ks<ksn; ++ks){
    float4 s0 = *(const float4*)(slots + ks*kstride + s);
    float4 s1 = *(const float4*)(slots + ks*kstride + s + 1024);
    a.x += s0.x + s1.x; a.y += s0.y + s1.y; a.z += s0.z + s1.z; a.w += s0.w + s1.w;
  }
  *(float4*)(out + b) = a;
}

extern "C" void kernel_launch(void* const* d_in, const int* in_sizes, int n_in,
                              void* d_out, int out_size, void* d_ws, size_t ws_size,
                              hipStream_t stream)
{
  (void)in_sizes; (void)n_in; (void)out_size; (void)ws_size;
  const float* x    = (const float*)d_in[0];
  const float* qkvw = (const float*)d_in[1];
  const float* outw = (const float*)d_in[2];
  const float* rw   = (const float*)d_in[3];
  const float* w1   = (const float*)d_in[4];
  const float* w2   = (const float*)d_in[5];
  const float* n1w  = (const float*)d_in[6];
  const float* n2w  = (const float*)d_in[7];
  float* out = (float*)d_out;

  char* base = (char*)d_ws;
  const size_t MB = 1ull<<20;
  const int KSO = 4;   // out-proj split-K
  const int KSW = 2;   // w2 split-K

  // region A [0,32MB): pre-MoE bf16 buffers; hid aliases the whole region later
  unsigned short* h_b  = (unsigned short*)(base + 0*MB);
  unsigned short* qb   = (unsigned short*)(base + 4*MB);
  unsigned short* kb   = (unsigned short*)(base + 8*MB);
  unsigned short* ob   = (unsigned short*)(base + 12*MB);
  unsigned short* qkvb = (unsigned short*)(base + 16*MB);   // 12MB
  unsigned short* hid  = (unsigned short*)(base + 0*MB);    // 32MB alias

  float* x1p   = (float*)(base + 32*MB);    // KSO x 8MB  -> [32,64)
  float* h2f   = (float*)(base + 64*MB);    // 8MB        -> [64,72)
  float* slots = (float*)(base + 72*MB);    // KSW x 16MB -> [72,104)
  float* x1    = (float*)(base + 136*MB);   // 8MB
  unsigned short* h2b = (unsigned short*)(base + 144*MB); // 4MB
  char* small_ = base + 148*MB;

  float* probs = (float*)(small_);
  int*   tope  = (int*)(small_ + 256*1024);
  float* topw  = (float*)(small_ + 512*1024);
  int*   tok_list = (int*)(small_ + 768*1024);
  float* wgt   = (float*)(small_ + 1024*1024);
  int*   counts= (int*)(small_ + 1536*1024);
  int*   offs  = (int*)(small_ + 1536*1024 + 256);
  int*   cursor= (int*)(small_ + 1536*1024 + 512);

  init_kernel<<<1,64,0,stream>>>(counts, cursor);
  rmsnorm_kernel<<<2048,256,0,stream>>>(x, n1w, h_b);
  // qkv: M=2048 N=3072 K=1024, MT=128 -> grid (16,12)
  gemm3<4,false,128><<<dim3(16,12,1),512,0,stream>>>(h_b,1024, qkvw,0,1024, 2048,3072,1024, 1,0,
      nullptr,nullptr,nullptr,nullptr,nullptr, nullptr,qkvb,3072);
  rope_kernel<<<2048,256,0,stream>>>(qkvb, qb, kb);
  attn_kernel<<<dim3(32,16),256,0,stream>>>(qb, kb, qkvb+2048, 3072, ob);
  // out-proj: M=2048 N=1024 K=1024 split KSO, MT=128 -> grid (16,4,4)
  gemm3<1,false,128><<<dim3(16,4,KSO),512,0,stream>>>(ob,1024, outw,0,1024, 2048,1024,1024, KSO,(long long)2048*1024,
      nullptr,nullptr,nullptr,nullptr, x, x1p,nullptr,1024);
  rmsnorm2_kernel<<<2048,256,0,stream>>>(x1p, KSO, (long long)2048*1024, n2w, x1, h2b, h2f);
  router_kernel<<<2048,256,0,stream>>>(h2f, rw, probs, tope, topw, counts);
  prefix_kernel<<<1,64,0,stream>>>(counts, offs);
  scatter_kernel<<<8,256,0,stream>>>(tope, topw, offs, cursor, tok_list, wgt);
  // w1: per-expert M<=2048 N=4096 K=1024, MT=256 -> grid (8,16,8)
  gemm3<2,true,256><<<dim3(8,16,8),512,0,stream>>>(h2b,1024, w1,(long long)4096*1024,1024, 2048,4096,1024, 1,0,
      counts,offs,tok_list,nullptr,nullptr, nullptr,hid,4096);
  // w2: per-expert M<=2048 N=1024 K=4096 split KSW, MT=256 -> grid (8,4,16)
  gemm3<3,false,256><<<dim3(8,4,8*KSW),512,0,stream>>>(hid,4096, w2,(long long)4096*1024,4096, 2048,1024,4096, KSW,(long long)4096*1024,
      counts,offs,tok_list,wgt,nullptr, slots,nullptr,1024);
  aux_kernel<<<1,256,0,stream>>>(probs, out);
  final_kernel<<<2048,256,0,stream>>>(x1, slots, KSW, (long long)4096*1024, out);
}

// Round 10
// 436.488 us; speedup vs baseline: 1.9878x; 1.1487x over previous
//
#include <hip/hip_runtime.h>
#include <cstdint>
#include <math.h>

typedef float f32x4 __attribute__((ext_vector_type(4)));
typedef __bf16 bf16x8 __attribute__((ext_vector_type(8)));
typedef unsigned short us4 __attribute__((ext_vector_type(4)));
typedef unsigned short us8 __attribute__((ext_vector_type(8)));

#define DEV static __device__ __forceinline__

DEV unsigned short f2bf(float f){
  union { __bf16 h; unsigned short u; } cv; cv.h = (__bf16)f; return cv.u;
}
DEV float bf2f(unsigned short u){ return __uint_as_float((unsigned int)u << 16); }

DEV void gload16(const void* g, void* l){
  __builtin_amdgcn_global_load_lds((__attribute__((address_space(1))) void*)g,
                                   (__attribute__((address_space(3))) void*)l, 16, 0, 0);
}

// ---------------- fp32 -> bf16 weight conversion (streaming) ----------------
__global__ __launch_bounds__(256) void conv_kernel(const float* __restrict__ src,
    unsigned short* __restrict__ dst, int n8){
  int i = blockIdx.x*256 + threadIdx.x;
  if (i >= n8) return;
  float4 a = ((const float4*)src)[2*i];
  float4 b = ((const float4*)src)[2*i+1];
  us8 o = { f2bf(a.x), f2bf(a.y), f2bf(a.z), f2bf(a.w),
            f2bf(b.x), f2bf(b.y), f2bf(b.z), f2bf(b.w) };
  ((us8*)dst)[i] = o;
}

// ---------------- RMSNorm 1 ----------------
__global__ __launch_bounds__(256) void rmsnorm_kernel(const float* __restrict__ x, const float* __restrict__ w,
    unsigned short* __restrict__ ob){
  int t = blockIdx.x, tid = threadIdx.x;
  float4 xv = *(const float4*)(x + (long long)t*1024 + tid*4);
  float ss = xv.x*xv.x + xv.y*xv.y + xv.z*xv.z + xv.w*xv.w;
  for (int m=32;m;m>>=1) ss += __shfl_xor(ss,m);
  __shared__ float lds[4];
  if ((tid&63)==0) lds[tid>>6] = ss;
  __syncthreads();
  float tot = lds[0]+lds[1]+lds[2]+lds[3];
  float inv = rsqrtf(tot*(1.0f/1024.0f) + 1.1920928955078125e-07f);
  float4 wv = *(const float4*)(w + tid*4);
  us4 rb = { f2bf(xv.x*inv*wv.x), f2bf(xv.y*inv*wv.y), f2bf(xv.z*inv*wv.z), f2bf(xv.w*inv*wv.w) };
  *(us4*)&ob[(long long)t*1024 + tid*4] = rb;
}

// ---------------- RMSNorm 2 ----------------
__global__ __launch_bounds__(256) void rmsnorm2_kernel(const float* __restrict__ xp, int ksn, long long kstride,
    const float* __restrict__ w, float* __restrict__ x1, unsigned short* __restrict__ hb, float* __restrict__ hf){
  int t = blockIdx.x, tid = threadIdx.x;
  long long b = (long long)t*1024 + tid*4;
  float4 xv = {0.f,0.f,0.f,0.f};
  for (int ks=0; ks<ksn; ++ks){
    float4 a = *(const float4*)(xp + ks*kstride + b);
    xv.x+=a.x; xv.y+=a.y; xv.z+=a.z; xv.w+=a.w;
  }
  *(float4*)(x1 + b) = xv;
  float ss = xv.x*xv.x + xv.y*xv.y + xv.z*xv.z + xv.w*xv.w;
  for (int m=32;m;m>>=1) ss += __shfl_xor(ss,m);
  __shared__ float lds[4];
  if ((tid&63)==0) lds[tid>>6] = ss;
  __syncthreads();
  float tot = lds[0]+lds[1]+lds[2]+lds[3];
  float inv = rsqrtf(tot*(1.0f/1024.0f) + 1.1920928955078125e-07f);
  float4 wv = *(const float4*)(w + tid*4);
  float r0 = xv.x*inv*wv.x, r1 = xv.y*inv*wv.y, r2 = xv.z*inv*wv.z, r3 = xv.w*inv*wv.w;
  us4 rb = { f2bf(r0), f2bf(r1), f2bf(r2), f2bf(r3) };
  *(us4*)&hb[b] = rb;
  float4 rf; rf.x=r0; rf.y=r1; rf.z=r2; rf.w=r3;
  *(float4*)(hf + b) = rf;
}

// ---------------- m97-replica GEMM  C[M,N] = A[M,K](bf16) * B[N,K]^T(bf16) ----------------
// 128x128 tile, 256 thr (4 waves 2x2), BK=64, SINGLE-buffered 32KB LDS,
// both operands via global_load_lds (width 16, pre-swizzled source c^(R&7)),
// plain __syncthreads 2-barrier loop; 3-4 blocks/CU provide the overlap (m114).
// EPI: 1 = fp32 (+resid if ks==0), 2 = gelu->bf16 rows rbase+lr, 3 = *wgt scatter, 4 = bf16
template<int EPI, bool GATHER>
__global__ __launch_bounds__(256) void gemm_bb(
    const unsigned short* __restrict__ A, int lda,
    const unsigned short* __restrict__ Bb, long long bstride, int ldb,
    int M, int N, int K, int KS, long long ksoff,
    const int* __restrict__ counts, const int* __restrict__ offs,
    const int* __restrict__ tok_list, const float* __restrict__ wgt,
    const float* __restrict__ resid,
    float* __restrict__ Cf, unsigned short* __restrict__ Cb, int ldc)
{
  const int z = blockIdx.z;
  const int e = z / KS, ks = z - e*KS;
  const int Me = counts ? counts[e] : M;
  const int by = blockIdx.y;
  if (by * 128 >= Me) return;
  const int rbase = offs ? offs[e] : 0;
  const int bx = blockIdx.x;
  const unsigned short* B = Bb + (long long)e * bstride;
  const int kn = K / KS;
  const int kbeg = ks * kn;

  __shared__ __align__(16) unsigned short As[128*64];
  __shared__ __align__(16) unsigned short Bs[128*64];

  const int tid = threadIdx.x, lane = tid & 63, w = tid >> 6;
  const int wr = w >> 1, wc = w & 1;
  const int l15 = lane & 15, l4 = lane >> 4;

  // staging sources: 4 gload16/thread each for A and B; dest linear chunk-slot G,
  // source chunk pre-swizzled sc = c ^ (R&7) so LDS holds swizzled layout
  const unsigned short* asrc[4];
  const unsigned short* bsrc[4];
  #pragma unroll
  for (int j=0;j<4;++j){
    int G = j*256 + tid;
    int R = G >> 3, c = G & 7;
    int sc = c ^ (R & 7);
    int lr = by*128 + R; if (lr >= Me) lr = Me-1;
    int li = rbase + lr;
    int ar = GATHER ? (tok_list[li] >> 1) : li;
    asrc[j] = A + (long long)ar*lda + kbeg + sc*8;
    bsrc[j] = B + (long long)(bx*128 + R)*ldb + kbeg + sc*8;
  }

  f32x4 acc[4][4] = {};

  for (int k0 = 0; k0 < kn; k0 += 64){
    __syncthreads();
    #pragma unroll
    for (int j=0;j<4;++j){
      gload16(asrc[j] + k0, &As[(j*256+tid)*8]);
      gload16(bsrc[j] + k0, &Bs[(j*256+tid)*8]);
    }
    __syncthreads();
    #pragma unroll
    for (int kk=0;kk<2;++kk){
      bf16x8 af[4], bfr[4];
      #pragma unroll
      for (int m=0;m<4;++m){
        int R = wr*64 + m*16 + l15;
        int c = (l4 + 4*kk) ^ (R&7);
        af[m] = *(const bf16x8*)&As[R*64 + c*8];
      }
      #pragma unroll
      for (int n=0;n<4;++n){
        int R = wc*64 + n*16 + l15;
        int c = (l4 + 4*kk) ^ (R&7);
        bfr[n] = *(const bf16x8*)&Bs[R*64 + c*8];
      }
      #pragma unroll
      for (int m=0;m<4;++m)
        #pragma unroll
        for (int n=0;n<4;++n)
          acc[m][n] = __builtin_amdgcn_mfma_f32_16x16x32_bf16(af[m], bfr[n], acc[m][n], 0, 0, 0);
    }
  }

  #pragma unroll
  for (int m=0;m<4;++m){
    #pragma unroll
    for (int r2=0;r2<4;++r2){
      int lr = by*128 + wr*64 + m*16 + 4*l4 + r2;
      if (lr >= Me) continue;
      #pragma unroll
      for (int n=0;n<4;++n){
        int col = bx*128 + wc*64 + n*16 + l15;
        float v = acc[m][n][r2];
        if constexpr (EPI == 1){
          if (ks == 0) v += resid[(long long)lr*ldc + col];
          Cf[ks*ksoff + (long long)lr*ldc + col] = v;
        } else if constexpr (EPI == 2){
          float g = 0.5f * v * (1.0f + erff(v * 0.70710678118654752f));
          Cb[(long long)(rbase+lr)*ldc + col] = f2bf(g);
        } else if constexpr (EPI == 3){
          int gi = rbase + lr;
          int ts = tok_list[gi];
          Cf[ks*ksoff + (long long)ts*ldc + col] = v * wgt[gi];
        } else {
          Cb[(long long)lr*ldc + col] = f2bf(v);
        }
      }
    }
  }
}

// ---------------- RoPE ----------------
__global__ __launch_bounds__(256) void rope_kernel(const unsigned short* __restrict__ qkvb,
    unsigned short* __restrict__ q, unsigned short* __restrict__ k){
  int t = blockIdx.x, tid = threadIdx.x;
  const unsigned short* row = qkvb + (long long)t*3072;
  #pragma unroll
  for (int u2=0; u2<2; ++u2){
    int pid = tid + u2*256;
    int hh = pid >> 5, j = pid & 31;
    float invf = __expf(-(float)j * 0.28782313662425575f);
    float fr = (float)t * invf;
    float sn, cs;
    __sincosf(fr, &sn, &cs);
    int base = hh*64 + j;
    long long ob_ = (long long)t*1024 + base;
    float a = bf2f(row[base]), b = bf2f(row[base+32]);
    q[ob_]    = f2bf(a*cs - b*sn);
    q[ob_+32] = f2bf(b*cs + a*sn);
    a = bf2f(row[1024+base]); b = bf2f(row[1024+base+32]);
    k[ob_]    = f2bf(a*cs - b*sn);
    k[ob_+32] = f2bf(b*cs + a*sn);
  }
}

// ---------------- causal flash attention ----------------
__global__ __launch_bounds__(256) void attn_kernel(
    const unsigned short* __restrict__ Q,
    const unsigned short* __restrict__ K,
    const unsigned short* __restrict__ V, int ldv,
    unsigned short* __restrict__ O)
{
  const int bx = blockIdx.x, h = blockIdx.y;
  const int q0 = bx*64;
  const int tid = threadIdx.x, lane = tid&63, w = tid>>6;

  __shared__ __align__(16) unsigned short Ks[64*64];
  __shared__ __align__(16) unsigned short Vs[64*64];
  __shared__ __align__(16) unsigned short Ps[4*16*64];
  unsigned short* Pw = Ps + w*1024;

  const int qrow = q0 + w*16 + (lane&15);
  bf16x8 aq[2];
  #pragma unroll
  for (int kk=0;kk<2;++kk)
    aq[kk] = *(const bf16x8*)&Q[(long long)qrow*1024 + h*64 + 32*kk + 8*(lane>>4)];

  f32x4 o[4] = {};
  float Mx[4] = {-INFINITY,-INFINITY,-INFINITY,-INFINITY};
  float Ls[4] = {0.f,0.f,0.f,0.f};

  const int row_g = q0 + w*16 + 4*(lane>>4);
  const int nt = bx + 1;
  for (int it = 0; it < nt; ++it){
    int k0 = it*64;
    #pragma unroll
    for (int i=0;i<2;++i){
      int seg = 4*i + w;
      int row = seg*8 + (lane>>3);
      int cs = (lane&7) ^ (row&7);
      gload16(&K[(long long)(k0+row)*1024 + h*64 + cs*8], &Ks[seg*512]);
      gload16(&V[(long long)(k0+row)*ldv  + h*64 + cs*8], &Vs[seg*512]);
    }
    __syncthreads();
    f32x4 st[4];
    #pragma unroll
    for (int kt=0;kt<4;++kt){
      f32x4 s = {0.f,0.f,0.f,0.f};
      #pragma unroll
      for (int kk=0;kk<2;++kk){
        int R = kt*16 + (lane&15);
        int ch = ((lane>>4)+4*kk) ^ (R&7);
        bf16x8 bk = *(const bf16x8*)&Ks[R*64 + ch*8];
        s = __builtin_amdgcn_mfma_f32_16x16x32_bf16(aq[kk], bk, s, 0,0,0);
      }
      st[kt] = s;
    }
    #pragma unroll
    for (int kt=0;kt<4;++kt){
      int col = k0 + kt*16 + (lane&15);
      #pragma unroll
      for (int r=0;r<4;++r){
        float vv = st[kt][r]*0.125f;
        st[kt][r] = (col <= row_g + r) ? vv : -INFINITY;
      }
    }
    float sf[4];
    #pragma unroll
    for (int r=0;r<4;++r){
      float mx = fmaxf(fmaxf(st[0][r],st[1][r]),fmaxf(st[2][r],st[3][r]));
      mx = fmaxf(mx, __shfl_xor(mx,1));
      mx = fmaxf(mx, __shfl_xor(mx,2));
      mx = fmaxf(mx, __shfl_xor(mx,4));
      mx = fmaxf(mx, __shfl_xor(mx,8));
      float mn = fmaxf(Mx[r], mx);
      float sc = __expf(Mx[r]-mn);
      Mx[r]=mn; sf[r]=sc;
      float ls=0.f;
      #pragma unroll
      for (int kt=0;kt<4;++kt){ float pp = __expf(st[kt][r]-mn); st[kt][r]=pp; ls+=pp; }
      Ls[r] = Ls[r]*sc + ls;
    }
    #pragma unroll
    for (int dt=0;dt<4;++dt)
      #pragma unroll
      for (int r=0;r<4;++r) o[dt][r] *= sf[r];
    #pragma unroll
    for (int kt=0;kt<4;++kt)
      #pragma unroll
      for (int r=0;r<4;++r){
        int prow = 4*(lane>>4)+r, pcol = kt*16+(lane&15);
        int byteoff = (prow*128 + pcol*2) ^ ((prow&7)<<4);
        *(unsigned short*)((char*)Pw + byteoff) = f2bf(st[kt][r]);
      }
    bf16x8 pa[2];
    #pragma unroll
    for (int kk=0;kk<2;++kk){
      int pr = lane&15;
      int ch = ((lane>>4)+4*kk) ^ (pr&7);
      pa[kk] = *(const bf16x8*)&Pw[pr*64 + ch*8];
    }
    #pragma unroll
    for (int dt=0;dt<4;++dt){
      #pragma unroll
      for (int kk=0;kk<2;++kk){
        union { unsigned short u[8]; bf16x8 v; } Ub;
        #pragma unroll
        for (int j=0;j<8;++j){
          int kr = 32*kk + 8*(lane>>4) + j;
          int d = dt*16 + (lane&15);
          int byteoff = (kr*128 + d*2) ^ ((kr&7)<<4);
          Ub.u[j] = *(const unsigned short*)((const char*)Vs + byteoff);
        }
        o[dt] = __builtin_amdgcn_mfma_f32_16x16x32_bf16(pa[kk], Ub.v, o[dt], 0,0,0);
      }
    }
    __syncthreads();
  }
  #pragma unroll
  for (int r=0;r<4;++r){
    float l = Ls[r];
    l += __shfl_xor(l,1); l += __shfl_xor(l,2); l += __shfl_xor(l,4); l += __shfl_xor(l,8);
    Ls[r] = 1.0f / l;
  }
  #pragma unroll
  for (int dt=0;dt<4;++dt)
    #pragma unroll
    for (int r=0;r<4;++r){
      float vv = o[dt][r]*Ls[r];
      int rg = row_g + r;
      O[(long long)rg*1024 + h*64 + dt*16 + (lane&15)] = f2bf(vv);
    }
}

// ---------------- router + top2 ----------------
__global__ __launch_bounds__(256) void router_kernel(const float* __restrict__ h2f, const float* __restrict__ rw,
    float* __restrict__ probs, int* __restrict__ tope, float* __restrict__ topw, int* __restrict__ counts){
  int t = blockIdx.x, tid = threadIdx.x;
  float4 hv = *(const float4*)(h2f + (long long)t*1024 + tid*4);
  float pe[8];
  #pragma unroll
  for (int e2=0;e2<8;++e2){
    float4 wv = *(const float4*)(rw + e2*1024 + tid*4);
    pe[e2] = hv.x*wv.x + hv.y*wv.y + hv.z*wv.z + hv.w*wv.w;
  }
  __shared__ float lds[32];
  #pragma unroll
  for (int e2=0;e2<8;++e2){
    float v = pe[e2];
    for (int m=32;m;m>>=1) v += __shfl_xor(v,m);
    if ((tid&63)==0) lds[(tid>>6)*8+e2] = v;
  }
  __syncthreads();
  if (tid==0){
    float lg[8], pp[8];
    #pragma unroll
    for (int e2=0;e2<8;++e2) lg[e2] = lds[e2]+lds[8+e2]+lds[16+e2]+lds[24+e2];
    float mx = lg[0];
    for (int e2=1;e2<8;++e2) mx = fmaxf(mx, lg[e2]);
    float s = 0.f;
    for (int e2=0;e2<8;++e2){ pp[e2] = __expf(lg[e2]-mx); s += pp[e2]; }
    float inv = 1.0f/s;
    int i0 = 0;
    for (int e2=1;e2<8;++e2) if (pp[e2] > pp[i0]) i0 = e2;
    int i1 = (i0==0)?1:0;
    for (int e2=0;e2<8;++e2) if (e2!=i0 && pp[e2] > pp[i1]) i1 = e2;
    for (int e2=0;e2<8;++e2) probs[t*8+e2] = pp[e2]*inv;
    float p0 = pp[i0], p1 = pp[i1], wsum = p0+p1;
    tope[t*2] = i0; tope[t*2+1] = i1;
    topw[t*2] = p0/wsum; topw[t*2+1] = p1/wsum;
    atomicAdd(&counts[i0],1); atomicAdd(&counts[i1],1);
  }
}

__global__ void init_kernel(int* counts, int* cursor){
  int i = threadIdx.x;
  if (i<8){ counts[i]=0; cursor[i]=0; }
}

__global__ void prefix_kernel(const int* counts, int* offs){
  if (threadIdx.x==0){
    int a=0;
    for (int e2=0;e2<8;++e2){ offs[e2]=a; a+=counts[e2]; }
  }
}

__global__ void scatter_kernel(const int* __restrict__ tope, const float* __restrict__ topw,
    const int* __restrict__ offs, int* __restrict__ cursor, int* __restrict__ tok_list, float* __restrict__ wgt){
  int t = blockIdx.x*blockDim.x + threadIdx.x;
  if (t >= 2048) return;
  #pragma unroll
  for (int s=0;s<2;++s){
    int e2 = tope[t*2+s];
    int pos = atomicAdd(&cursor[e2], 1);
    int i = offs[e2] + pos;
    tok_list[i] = t*2+s;
    wgt[i] = topw[t*2+s];
  }
}

__global__ __launch_bounds__(256) void aux_kernel(const float* __restrict__ probs, float* __restrict__ out){
  int tid = threadIdx.x;
  float pe[8] = {0,0,0,0,0,0,0,0};
  for (int t = tid; t < 2048; t += 256){
    #pragma unroll
    for (int e2=0;e2<8;++e2) pe[e2] += probs[t*8+e2];
  }
  __shared__ float lds[32];
  #pragma unroll
  for (int e2=0;e2<8;++e2){
    float v = pe[e2];
    for (int m=32;m;m>>=1) v += __shfl_xor(v,m);
    if ((tid&63)==0) lds[(tid>>6)*8 + e2] = v;
  }
  __syncthreads();
  if (tid==0){
    float aux = 0.f;
    #pragma unroll
    for (int e2=0;e2<8;++e2){
      float mean = (lds[e2]+lds[8+e2]+lds[16+e2]+lds[24+e2]) * (1.0f/2048.0f);
      aux += mean*mean;
    }
    out[2097152] = 8.0f * aux;
  }
}

__global__ __launch_bounds__(256) void final_kernel(const float* __restrict__ x1, const float* __restrict__ slots,
    int ksn, long long kstride, float* __restrict__ out){
  int t = blockIdx.x, tid = threadIdx.x;
  long long b = (long long)t*1024 + tid*4;
  float4 a = *(const float4*)(x1 + b);
  long long s = (long long)t*2048 + tid*4;
  for (int ks=0; ks<ksn; ++ks){
    float4 s0 = *(const float4*)(slots + ks*kstride + s);
    float4 s1 = *(const float4*)(slots + ks*kstride + s + 1024);
    a.x += s0.x + s1.x; a.y += s0.y + s1.y; a.z += s0.z + s1.z; a.w += s0.w + s1.w;
  }
  *(float4*)(out + b) = a;
}

extern "C" void kernel_launch(void* const* d_in, const int* in_sizes, int n_in,
                              void* d_out, int out_size, void* d_ws, size_t ws_size,
                              hipStream_t stream)
{
  (void)in_sizes; (void)n_in; (void)out_size; (void)ws_size;
  const float* x    = (const float*)d_in[0];
  const float* qkvw = (const float*)d_in[1];
  const float* outw = (const float*)d_in[2];
  const float* rw   = (const float*)d_in[3];
  const float* w1   = (const float*)d_in[4];
  const float* w2   = (const float*)d_in[5];
  const float* n1w  = (const float*)d_in[6];
  const float* n2w  = (const float*)d_in[7];
  float* out = (float*)d_out;

  char* base = (char*)d_ws;
  const size_t MB = 1ull<<20;
  const int KSO = 4;   // out-proj split-K
  const int KSW = 2;   // w2 split-K

  // [0,32MB): pre-MoE bf16 activation buffers; hid aliases whole region after attn phase
  unsigned short* h_b  = (unsigned short*)(base + 0*MB);
  unsigned short* qb   = (unsigned short*)(base + 4*MB);
  unsigned short* kb   = (unsigned short*)(base + 8*MB);
  unsigned short* ob   = (unsigned short*)(base + 12*MB);
  unsigned short* qkvb = (unsigned short*)(base + 16*MB);   // 12MB
  unsigned short* hid  = (unsigned short*)(base + 0*MB);    // 32MB alias

  // [32,96MB): bf16 weight region (reused serially): wbq+wbo early, then w1, then w2
  unsigned short* wbq = (unsigned short*)(base + 32*MB);    // 6MB
  unsigned short* wbo = (unsigned short*)(base + 40*MB);    // 2MB
  unsigned short* wb  = (unsigned short*)(base + 32*MB);    // 64MB (w1 then w2)

  // [96,128): out-proj fp32 partials (KSO x 8MB); slots aliases after rmsnorm2
  float* x1p   = (float*)(base + 96*MB);
  float* slots = (float*)(base + 96*MB);    // KSW x 16MB
  float* h2f   = (float*)(base + 128*MB);   // 8MB
  float* x1    = (float*)(base + 136*MB);   // 8MB
  unsigned short* h2b = (unsigned short*)(base + 144*MB);   // 4MB
  char* small_ = base + 148*MB;

  float* probs = (float*)(small_);
  int*   tope  = (int*)(small_ + 256*1024);
  float* topw  = (float*)(small_ + 512*1024);
  int*   tok_list = (int*)(small_ + 768*1024);
  float* wgt   = (float*)(small_ + 1024*1024);
  int*   counts= (int*)(small_ + 1536*1024);
  int*   offs  = (int*)(small_ + 1536*1024 + 256);
  int*   cursor= (int*)(small_ + 1536*1024 + 512);

  init_kernel<<<1,64,0,stream>>>(counts, cursor);
  rmsnorm_kernel<<<2048,256,0,stream>>>(x, n1w, h_b);
  conv_kernel<<<1536,256,0,stream>>>(qkvw, wbq, 3*1024*1024/8);
  conv_kernel<<<512,256,0,stream>>>(outw, wbo, 1024*1024/8);
  // qkv: M=2048 N=3072 K=1024 -> grid (bxN=24, byM=16)
  gemm_bb<4,false><<<dim3(24,16,1),256,0,stream>>>(h_b,1024, wbq,0,1024, 2048,3072,1024, 1,0,
      nullptr,nullptr,nullptr,nullptr,nullptr, nullptr,qkvb,3072);
  rope_kernel<<<2048,256,0,stream>>>(qkvb, qb, kb);
  attn_kernel<<<dim3(32,16),256,0,stream>>>(qb, kb, qkvb+2048, 3072, ob);
  // out-proj: M=2048 N=1024 K=1024 split KSO -> grid (8,16,4)
  gemm_bb<1,false><<<dim3(8,16,KSO),256,0,stream>>>(ob,1024, wbo,0,1024, 2048,1024,1024, KSO,(long long)2048*1024,
      nullptr,nullptr,nullptr,nullptr, x, x1p,nullptr,1024);
  rmsnorm2_kernel<<<2048,256,0,stream>>>(x1p, KSO, (long long)2048*1024, n2w, x1, h2b, h2f);
  router_kernel<<<2048,256,0,stream>>>(h2f, rw, probs, tope, topw, counts);
  prefix_kernel<<<1,64,0,stream>>>(counts, offs);
  scatter_kernel<<<8,256,0,stream>>>(tope, topw, offs, cursor, tok_list, wgt);
  // w1 weights -> bf16, then w1 GEMM: per-expert M<=2048 N=4096 K=1024 -> grid (32,16,8)
  conv_kernel<<<16384,256,0,stream>>>(w1, wb, 32*1024*1024/8);
  gemm_bb<2,true><<<dim3(32,16,8),256,0,stream>>>(h2b,1024, wb,(long long)4096*1024,1024, 2048,4096,1024, 1,0,
      counts,offs,tok_list,nullptr,nullptr, nullptr,hid,4096);
  // w2 weights -> bf16, then w2 GEMM: per-expert M<=2048 N=1024 K=4096 split KSW -> grid (8,16,16)
  conv_kernel<<<16384,256,0,stream>>>(w2, wb, 32*1024*1024/8);
  gemm_bb<3,false><<<dim3(8,16,8*KSW),256,0,stream>>>(hid,4096, wb,(long long)4096*1024,4096, 2048,1024,4096, KSW,(long long)4096*1024,
      counts,offs,tok_list,wgt,nullptr, slots,nullptr,1024);
  aux_kernel<<<1,256,0,stream>>>(probs, out);
  final_kernel<<<2048,256,0,stream>>>(x1, slots, KSW, (long long)4096*1024, out);
}

// Round 11
// 419.036 us; speedup vs baseline: 2.0705x; 1.0416x over previous
//
#include <hip/hip_runtime.h>
#include <cstdint>
#include <math.h>

typedef float f32x4 __attribute__((ext_vector_type(4)));
typedef __bf16 bf16x8 __attribute__((ext_vector_type(8)));
typedef unsigned short us4 __attribute__((ext_vector_type(4)));
typedef unsigned short us8 __attribute__((ext_vector_type(8)));

#define DEV static __device__ __forceinline__

DEV unsigned short f2bf(float f){
  union { __bf16 h; unsigned short u; } cv; cv.h = (__bf16)f; return cv.u;
}
DEV float bf2f(unsigned short u){ return __uint_as_float((unsigned int)u << 16); }

DEV void gload16(const void* g, void* l){
  __builtin_amdgcn_global_load_lds((__attribute__((address_space(1))) void*)g,
                                   (__attribute__((address_space(3))) void*)l, 16, 0, 0);
}

// ---------------- fp32 -> bf16 weight conversion (streaming) ----------------
__global__ __launch_bounds__(256) void conv_kernel(const float* __restrict__ src,
    unsigned short* __restrict__ dst, int n8){
  int i = blockIdx.x*256 + threadIdx.x;
  if (i >= n8) return;
  float4 a = ((const float4*)src)[2*i];
  float4 b = ((const float4*)src)[2*i+1];
  us8 o = { f2bf(a.x), f2bf(a.y), f2bf(a.z), f2bf(a.w),
            f2bf(b.x), f2bf(b.y), f2bf(b.z), f2bf(b.w) };
  ((us8*)dst)[i] = o;
}

// ---------------- V transpose: qkvb V part [t][h*64+d] -> vt[h][d][t] ----------------
__global__ __launch_bounds__(256) void vtrans_kernel(const unsigned short* __restrict__ qkvb,
    unsigned short* __restrict__ vt){
  int tt = blockIdx.x, h = blockIdx.y;
  int t0 = tt*64;
  __shared__ unsigned short tile[64][72];
  int r = threadIdx.x >> 2, cb = (threadIdx.x & 3) * 16;
  const unsigned short* src = qkvb + (long long)(t0+r)*3072 + 2048 + h*64 + cb;
  us8 a = *(const us8*)src;
  us8 b = *(const us8*)(src+8);
  #pragma unroll
  for (int i=0;i<8;++i){ tile[r][cb+i] = a[i]; tile[r][cb+8+i] = b[i]; }
  __syncthreads();
  unsigned short o[16];
  #pragma unroll
  for (int i=0;i<16;++i) o[i] = tile[cb+i][r];
  unsigned short* dst = vt + (long long)(h*64+r)*2048 + t0 + cb;
  *(us8*)dst = *(us8*)&o[0];
  *(us8*)(dst+8) = *(us8*)&o[8];
}

// ---------------- RMSNorm 1 ----------------
__global__ __launch_bounds__(256) void rmsnorm_kernel(const float* __restrict__ x, const float* __restrict__ w,
    unsigned short* __restrict__ ob){
  int t = blockIdx.x, tid = threadIdx.x;
  float4 xv = *(const float4*)(x + (long long)t*1024 + tid*4);
  float ss = xv.x*xv.x + xv.y*xv.y + xv.z*xv.z + xv.w*xv.w;
  for (int m=32;m;m>>=1) ss += __shfl_xor(ss,m);
  __shared__ float lds[4];
  if ((tid&63)==0) lds[tid>>6] = ss;
  __syncthreads();
  float tot = lds[0]+lds[1]+lds[2]+lds[3];
  float inv = rsqrtf(tot*(1.0f/1024.0f) + 1.1920928955078125e-07f);
  float4 wv = *(const float4*)(w + tid*4);
  us4 rb = { f2bf(xv.x*inv*wv.x), f2bf(xv.y*inv*wv.y), f2bf(xv.z*inv*wv.z), f2bf(xv.w*inv*wv.w) };
  *(us4*)&ob[(long long)t*1024 + tid*4] = rb;
}

// ---------------- RMSNorm 2 ----------------
__global__ __launch_bounds__(256) void rmsnorm2_kernel(const float* __restrict__ xp, int ksn, long long kstride,
    const float* __restrict__ w, float* __restrict__ x1, unsigned short* __restrict__ hb, float* __restrict__ hf){
  int t = blockIdx.x, tid = threadIdx.x;
  long long b = (long long)t*1024 + tid*4;
  float4 xv = {0.f,0.f,0.f,0.f};
  for (int ks=0; ks<ksn; ++ks){
    float4 a = *(const float4*)(xp + ks*kstride + b);
    xv.x+=a.x; xv.y+=a.y; xv.z+=a.z; xv.w+=a.w;
  }
  *(float4*)(x1 + b) = xv;
  float ss = xv.x*xv.x + xv.y*xv.y + xv.z*xv.z + xv.w*xv.w;
  for (int m=32;m;m>>=1) ss += __shfl_xor(ss,m);
  __shared__ float lds[4];
  if ((tid&63)==0) lds[tid>>6] = ss;
  __syncthreads();
  float tot = lds[0]+lds[1]+lds[2]+lds[3];
  float inv = rsqrtf(tot*(1.0f/1024.0f) + 1.1920928955078125e-07f);
  float4 wv = *(const float4*)(w + tid*4);
  float r0 = xv.x*inv*wv.x, r1 = xv.y*inv*wv.y, r2 = xv.z*inv*wv.z, r3 = xv.w*inv*wv.w;
  us4 rb = { f2bf(r0), f2bf(r1), f2bf(r2), f2bf(r3) };
  *(us4*)&hb[b] = rb;
  float4 rf; rf.x=r0; rf.y=r1; rf.z=r2; rf.w=r3;
  *(float4*)(hf + b) = rf;
}

// ---------------- m97-replica GEMM  C[M,N] = A[M,K](bf16) * B[N,K]^T(bf16) ----------------
template<int EPI, bool GATHER>
__global__ __launch_bounds__(256) void gemm_bb(
    const unsigned short* __restrict__ A, int lda,
    const unsigned short* __restrict__ Bb, long long bstride, int ldb,
    int M, int N, int K, int KS, long long ksoff,
    const int* __restrict__ counts, const int* __restrict__ offs,
    const int* __restrict__ tok_list, const float* __restrict__ wgt,
    const float* __restrict__ resid,
    float* __restrict__ Cf, unsigned short* __restrict__ Cb, int ldc)
{
  const int z = blockIdx.z;
  const int e = z / KS, ks = z - e*KS;
  const int Me = counts ? counts[e] : M;
  const int by = blockIdx.y;
  if (by * 128 >= Me) return;
  const int rbase = offs ? offs[e] : 0;
  const int bx = blockIdx.x;
  const unsigned short* B = Bb + (long long)e * bstride;
  const int kn = K / KS;
  const int kbeg = ks * kn;

  __shared__ __align__(16) unsigned short As[128*64];
  __shared__ __align__(16) unsigned short Bs[128*64];

  const int tid = threadIdx.x, lane = tid & 63, w = tid >> 6;
  const int wr = w >> 1, wc = w & 1;
  const int l15 = lane & 15, l4 = lane >> 4;

  const unsigned short* asrc[4];
  const unsigned short* bsrc[4];
  #pragma unroll
  for (int j=0;j<4;++j){
    int G = j*256 + tid;
    int R = G >> 3, c = G & 7;
    int sc = c ^ (R & 7);
    int lr = by*128 + R; if (lr >= Me) lr = Me-1;
    int li = rbase + lr;
    int ar = GATHER ? (tok_list[li] >> 1) : li;
    asrc[j] = A + (long long)ar*lda + kbeg + sc*8;
    bsrc[j] = B + (long long)(bx*128 + R)*ldb + kbeg + sc*8;
  }

  f32x4 acc[4][4] = {};

  for (int k0 = 0; k0 < kn; k0 += 64){
    __syncthreads();
    #pragma unroll
    for (int j=0;j<4;++j){
      gload16(asrc[j] + k0, &As[(j*256+tid)*8]);
      gload16(bsrc[j] + k0, &Bs[(j*256+tid)*8]);
    }
    __syncthreads();
    #pragma unroll
    for (int kk=0;kk<2;++kk){
      bf16x8 af[4], bfr[4];
      #pragma unroll
      for (int m=0;m<4;++m){
        int R = wr*64 + m*16 + l15;
        int c = (l4 + 4*kk) ^ (R&7);
        af[m] = *(const bf16x8*)&As[R*64 + c*8];
      }
      #pragma unroll
      for (int n=0;n<4;++n){
        int R = wc*64 + n*16 + l15;
        int c = (l4 + 4*kk) ^ (R&7);
        bfr[n] = *(const bf16x8*)&Bs[R*64 + c*8];
      }
      #pragma unroll
      for (int m=0;m<4;++m)
        #pragma unroll
        for (int n=0;n<4;++n)
          acc[m][n] = __builtin_amdgcn_mfma_f32_16x16x32_bf16(af[m], bfr[n], acc[m][n], 0, 0, 0);
    }
  }

  #pragma unroll
  for (int m=0;m<4;++m){
    #pragma unroll
    for (int r2=0;r2<4;++r2){
      int lr = by*128 + wr*64 + m*16 + 4*l4 + r2;
      if (lr >= Me) continue;
      #pragma unroll
      for (int n=0;n<4;++n){
        int col = bx*128 + wc*64 + n*16 + l15;
        float v = acc[m][n][r2];
        if constexpr (EPI == 1){
          if (ks == 0) v += resid[(long long)lr*ldc + col];
          Cf[ks*ksoff + (long long)lr*ldc + col] = v;
        } else if constexpr (EPI == 2){
          float g = 0.5f * v * (1.0f + erff(v * 0.70710678118654752f));
          Cb[(long long)(rbase+lr)*ldc + col] = f2bf(g);
        } else if constexpr (EPI == 3){
          int gi = rbase + lr;
          int ts = tok_list[gi];
          Cf[ks*ksoff + (long long)ts*ldc + col] = v * wgt[gi];
        } else {
          Cb[(long long)lr*ldc + col] = f2bf(v);
        }
      }
    }
  }
}

// ---------------- RoPE ----------------
__global__ __launch_bounds__(256) void rope_kernel(const unsigned short* __restrict__ qkvb,
    unsigned short* __restrict__ q, unsigned short* __restrict__ k){
  int t = blockIdx.x, tid = threadIdx.x;
  const unsigned short* row = qkvb + (long long)t*3072;
  #pragma unroll
  for (int u2=0; u2<2; ++u2){
    int pid = tid + u2*256;
    int hh = pid >> 5, j = pid & 31;
    float invf = __expf(-(float)j * 0.28782313662425575f);
    float fr = (float)t * invf;
    float sn, cs;
    __sincosf(fr, &sn, &cs);
    int base = hh*64 + j;
    long long ob_ = (long long)t*1024 + base;
    float a = bf2f(row[base]), b = bf2f(row[base+32]);
    q[ob_]    = f2bf(a*cs - b*sn);
    q[ob_+32] = f2bf(b*cs + a*sn);
    a = bf2f(row[1024+base]); b = bf2f(row[1024+base+32]);
    k[ob_]    = f2bf(a*cs - b*sn);
    k[ob_+32] = f2bf(b*cs + a*sn);
  }
}

// ---------------- causal flash attention (V^T in vt[h][d][t]) ----------------
__global__ __launch_bounds__(256) void attn_kernel(
    const unsigned short* __restrict__ Q,
    const unsigned short* __restrict__ K,
    const unsigned short* __restrict__ Vt,
    unsigned short* __restrict__ O)
{
  const int bx = gridDim.x - 1 - blockIdx.x;   // longest blocks dispatch first
  const int h = blockIdx.y;
  const int q0 = bx*64;
  const int tid = threadIdx.x, lane = tid&63, w = tid>>6;
  const int l15 = lane & 15, l4 = lane >> 4;

  __shared__ __align__(16) unsigned short Ks[64*64];
  __shared__ __align__(16) unsigned short Vs[64*64];
  __shared__ __align__(16) unsigned short Ps[4*16*64];
  unsigned short* Pw = Ps + w*1024;

  const int qrow = q0 + w*16 + l15;
  bf16x8 aq[2];
  #pragma unroll
  for (int kk=0;kk<2;++kk)
    aq[kk] = *(const bf16x8*)&Q[(long long)qrow*1024 + h*64 + 32*kk + 8*l4];

  f32x4 o[4] = {};
  float Mx[4] = {-INFINITY,-INFINITY,-INFINITY,-INFINITY};
  float Ls[4] = {0.f,0.f,0.f,0.f};

  const int row_g = q0 + w*16 + 4*l4;
  const int nt = bx + 1;
  for (int it = 0; it < nt; ++it){
    int k0 = it*64;
    #pragma unroll
    for (int i=0;i<2;++i){
      int seg = 4*i + w;
      int row = seg*8 + (lane>>3);
      int cs = (lane&7) ^ (row&7);
      gload16(&K[(long long)(k0+row)*1024 + h*64 + cs*8], &Ks[seg*512]);
      gload16(&Vt[(long long)(h*64+row)*2048 + k0 + cs*8], &Vs[seg*512]);
    }
    __syncthreads();
    f32x4 st[4];
    #pragma unroll
    for (int kt=0;kt<4;++kt){
      f32x4 s = {0.f,0.f,0.f,0.f};
      #pragma unroll
      for (int kk=0;kk<2;++kk){
        int R = kt*16 + l15;
        int ch = (l4+4*kk) ^ (R&7);
        bf16x8 bk = *(const bf16x8*)&Ks[R*64 + ch*8];
        s = __builtin_amdgcn_mfma_f32_16x16x32_bf16(aq[kk], bk, s, 0,0,0);
      }
      st[kt] = s;
    }
    #pragma unroll
    for (int kt=0;kt<4;++kt){
      int col = k0 + kt*16 + l15;
      #pragma unroll
      for (int r=0;r<4;++r){
        float vv = st[kt][r]*0.125f;
        st[kt][r] = (col <= row_g + r) ? vv : -INFINITY;
      }
    }
    float sf[4];
    #pragma unroll
    for (int r=0;r<4;++r){
      float mx = fmaxf(fmaxf(st[0][r],st[1][r]),fmaxf(st[2][r],st[3][r]));
      mx = fmaxf(mx, __shfl_xor(mx,1));
      mx = fmaxf(mx, __shfl_xor(mx,2));
      mx = fmaxf(mx, __shfl_xor(mx,4));
      mx = fmaxf(mx, __shfl_xor(mx,8));
      float mn = fmaxf(Mx[r], mx);
      float sc = __expf(Mx[r]-mn);
      Mx[r]=mn; sf[r]=sc;
      float ls=0.f;
      #pragma unroll
      for (int kt=0;kt<4;++kt){ float pp = __expf(st[kt][r]-mn); st[kt][r]=pp; ls+=pp; }
      Ls[r] = Ls[r]*sc + ls;
    }
    #pragma unroll
    for (int dt=0;dt<4;++dt)
      #pragma unroll
      for (int r=0;r<4;++r) o[dt][r] *= sf[r];
    #pragma unroll
    for (int kt=0;kt<4;++kt)
      #pragma unroll
      for (int r=0;r<4;++r){
        int prow = 4*l4+r, pcol = kt*16+l15;
        int byteoff = (prow*128 + pcol*2) ^ ((prow&7)<<4);
        *(unsigned short*)((char*)Pw + byteoff) = f2bf(st[kt][r]);
      }
    bf16x8 pa[2];
    #pragma unroll
    for (int kk=0;kk<2;++kk){
      int pr = l15;
      int ch = (l4+4*kk) ^ (pr&7);
      pa[kk] = *(const bf16x8*)&Pw[pr*64 + ch*8];
    }
    #pragma unroll
    for (int dt=0;dt<4;++dt){
      #pragma unroll
      for (int kk=0;kk<2;++kk){
        int R = dt*16 + l15;
        int c = (l4 + 4*kk) ^ (R&7);
        bf16x8 bv = *(const bf16x8*)&Vs[R*64 + c*8];
        o[dt] = __builtin_amdgcn_mfma_f32_16x16x32_bf16(pa[kk], bv, o[dt], 0,0,0);
      }
    }
    __syncthreads();
  }
  #pragma unroll
  for (int r=0;r<4;++r){
    float l = Ls[r];
    l += __shfl_xor(l,1); l += __shfl_xor(l,2); l += __shfl_xor(l,4); l += __shfl_xor(l,8);
    Ls[r] = 1.0f / l;
  }
  #pragma unroll
  for (int dt=0;dt<4;++dt)
    #pragma unroll
    for (int r=0;r<4;++r){
      float vv = o[dt][r]*Ls[r];
      int rg = row_g + r;
      O[(long long)rg*1024 + h*64 + dt*16 + l15] = f2bf(vv);
    }
}

// ---------------- router + top2 ----------------
__global__ __launch_bounds__(256) void router_kernel(const float* __restrict__ h2f, const float* __restrict__ rw,
    float* __restrict__ probs, int* __restrict__ tope, float* __restrict__ topw, int* __restrict__ counts){
  int t = blockIdx.x, tid = threadIdx.x;
  float4 hv = *(const float4*)(h2f + (long long)t*1024 + tid*4);
  float pe[8];
  #pragma unroll
  for (int e2=0;e2<8;++e2){
    float4 wv = *(const float4*)(rw + e2*1024 + tid*4);
    pe[e2] = hv.x*wv.x + hv.y*wv.y + hv.z*wv.z + hv.w*wv.w;
  }
  __shared__ float lds[32];
  #pragma unroll
  for (int e2=0;e2<8;++e2){
    float v = pe[e2];
    for (int m=32;m;m>>=1) v += __shfl_xor(v,m);
    if ((tid&63)==0) lds[(tid>>6)*8+e2] = v;
  }
  __syncthreads();
  if (tid==0){
    float lg[8], pp[8];
    #pragma unroll
    for (int e2=0;e2<8;++e2) lg[e2] = lds[e2]+lds[8+e2]+lds[16+e2]+lds[24+e2];
    float mx = lg[0];
    for (int e2=1;e2<8;++e2) mx = fmaxf(mx, lg[e2]);
    float s = 0.f;
    for (int e2=0;e2<8;++e2){ pp[e2] = __expf(lg[e2]-mx); s += pp[e2]; }
    float inv = 1.0f/s;
    int i0 = 0;
    for (int e2=1;e2<8;++e2) if (pp[e2] > pp[i0]) i0 = e2;
    int i1 = (i0==0)?1:0;
    for (int e2=0;e2<8;++e2) if (e2!=i0 && pp[e2] > pp[i1]) i1 = e2;
    for (int e2=0;e2<8;++e2) probs[t*8+e2] = pp[e2]*inv;
    float p0 = pp[i0], p1 = pp[i1], wsum = p0+p1;
    tope[t*2] = i0; tope[t*2+1] = i1;
    topw[t*2] = p0/wsum; topw[t*2+1] = p1/wsum;
    atomicAdd(&counts[i0],1); atomicAdd(&counts[i1],1);
  }
}

__global__ void init_kernel(int* counts, int* cursor){
  int i = threadIdx.x;
  if (i<8){ counts[i]=0; cursor[i]=0; }
}

__global__ void prefix_kernel(const int* counts, int* offs){
  if (threadIdx.x==0){
    int a=0;
    for (int e2=0;e2<8;++e2){ offs[e2]=a; a+=counts[e2]; }
  }
}

__global__ void scatter_kernel(const int* __restrict__ tope, const float* __restrict__ topw,
    const int* __restrict__ offs, int* __restrict__ cursor, int* __restrict__ tok_list, float* __restrict__ wgt){
  int t = blockIdx.x*blockDim.x + threadIdx.x;
  if (t >= 2048) return;
  #pragma unroll
  for (int s=0;s<2;++s){
    int e2 = tope[t*2+s];
    int pos = atomicAdd(&cursor[e2], 1);
    int i = offs[e2] + pos;
    tok_list[i] = t*2+s;
    wgt[i] = topw[t*2+s];
  }
}

__global__ __launch_bounds__(256) void aux_kernel(const float* __restrict__ probs, float* __restrict__ out){
  int tid = threadIdx.x;
  float pe[8] = {0,0,0,0,0,0,0,0};
  for (int t = tid; t < 2048; t += 256){
    #pragma unroll
    for (int e2=0;e2<8;++e2) pe[e2] += probs[t*8+e2];
  }
  __shared__ float lds[32];
  #pragma unroll
  for (int e2=0;e2<8;++e2){
    float v = pe[e2];
    for (int m=32;m;m>>=1) v += __shfl_xor(v,m);
    if ((tid&63)==0) lds[(tid>>6)*8 + e2] = v;
  }
  __syncthreads();
  if (tid==0){
    float aux = 0.f;
    #pragma unroll
    for (int e2=0;e2<8;++e2){
      float mean = (lds[e2]+lds[8+e2]+lds[16+e2]+lds[24+e2]) * (1.0f/2048.0f);
      aux += mean*mean;
    }
    out[2097152] = 8.0f * aux;
  }
}

__global__ __launch_bounds__(256) void final_kernel(const float* __restrict__ x1, const float* __restrict__ slots,
    int ksn, long long kstride, float* __restrict__ out){
  int t = blockIdx.x, tid = threadIdx.x;
  long long b = (long long)t*1024 + tid*4;
  float4 a = *(const float4*)(x1 + b);
  long long s = (long long)t*2048 + tid*4;
  for (int ks=0; ks<ksn; ++ks){
    float4 s0 = *(const float4*)(slots + ks*kstride + s);
    float4 s1 = *(const float4*)(slots + ks*kstride + s + 1024);
    a.x += s0.x + s1.x; a.y += s0.y + s1.y; a.z += s0.z + s1.z; a.w += s0.w + s1.w;
  }
  *(float4*)(out + b) = a;
}

extern "C" void kernel_launch(void* const* d_in, const int* in_sizes, int n_in,
                              void* d_out, int out_size, void* d_ws, size_t ws_size,
                              hipStream_t stream)
{
  (void)in_sizes; (void)n_in; (void)out_size; (void)ws_size;
  const float* x    = (const float*)d_in[0];
  const float* qkvw = (const float*)d_in[1];
  const float* outw = (const float*)d_in[2];
  const float* rw   = (const float*)d_in[3];
  const float* w1   = (const float*)d_in[4];
  const float* w2   = (const float*)d_in[5];
  const float* n1w  = (const float*)d_in[6];
  const float* n2w  = (const float*)d_in[7];
  float* out = (float*)d_out;

  char* base = (char*)d_ws;
  const size_t MB = 1ull<<20;
  const int KSO = 4;   // out-proj split-K
  const int KSW = 2;   // w2 split-K

  // [0,32MB): pre-MoE bf16 activation buffers; hid aliases whole region after attn phase
  unsigned short* h_b  = (unsigned short*)(base + 0*MB);
  unsigned short* qb   = (unsigned short*)(base + 4*MB);
  unsigned short* kb   = (unsigned short*)(base + 8*MB);
  unsigned short* ob   = (unsigned short*)(base + 12*MB);
  unsigned short* qkvb = (unsigned short*)(base + 16*MB);   // 12MB
  unsigned short* vt   = (unsigned short*)(base + 28*MB);   // 4MB
  unsigned short* hid  = (unsigned short*)(base + 0*MB);    // 32MB alias

  // [32,96MB): bf16 weight region (reused serially): wbq+wbo early, then w1, then w2
  unsigned short* wbq = (unsigned short*)(base + 32*MB);    // 6MB
  unsigned short* wbo = (unsigned short*)(base + 40*MB);    // 2MB
  unsigned short* wb  = (unsigned short*)(base + 32*MB);    // 64MB (w1 then w2)

  // [96,128): out-proj fp32 partials (KSO x 8MB); slots aliases after rmsnorm2
  float* x1p   = (float*)(base + 96*MB);
  float* slots = (float*)(base + 96*MB);    // KSW x 16MB
  float* h2f   = (float*)(base + 128*MB);   // 8MB
  float* x1    = (float*)(base + 136*MB);   // 8MB
  unsigned short* h2b = (unsigned short*)(base + 144*MB);   // 4MB
  char* small_ = base + 148*MB;

  float* probs = (float*)(small_);
  int*   tope  = (int*)(small_ + 256*1024);
  float* topw  = (float*)(small_ + 512*1024);
  int*   tok_list = (int*)(small_ + 768*1024);
  float* wgt   = (float*)(small_ + 1024*1024);
  int*   counts= (int*)(small_ + 1536*1024);
  int*   offs  = (int*)(small_ + 1536*1024 + 256);
  int*   cursor= (int*)(small_ + 1536*1024 + 512);

  init_kernel<<<1,64,0,stream>>>(counts, cursor);
  rmsnorm_kernel<<<2048,256,0,stream>>>(x, n1w, h_b);
  conv_kernel<<<1536,256,0,stream>>>(qkvw, wbq, 3*1024*1024/8);
  conv_kernel<<<512,256,0,stream>>>(outw, wbo, 1024*1024/8);
  // qkv: M=2048 N=3072 K=1024 -> grid (bxN=24, byM=16)
  gemm_bb<4,false><<<dim3(24,16,1),256,0,stream>>>(h_b,1024, wbq,0,1024, 2048,3072,1024, 1,0,
      nullptr,nullptr,nullptr,nullptr,nullptr, nullptr,qkvb,3072);
  rope_kernel<<<2048,256,0,stream>>>(qkvb, qb, kb);
  vtrans_kernel<<<dim3(32,16),256,0,stream>>>(qkvb, vt);
  attn_kernel<<<dim3(32,16),256,0,stream>>>(qb, kb, vt, ob);
  // out-proj: M=2048 N=1024 K=1024 split KSO -> grid (8,16,4)
  gemm_bb<1,false><<<dim3(8,16,KSO),256,0,stream>>>(ob,1024, wbo,0,1024, 2048,1024,1024, KSO,(long long)2048*1024,
      nullptr,nullptr,nullptr,nullptr, x, x1p,nullptr,1024);
  rmsnorm2_kernel<<<2048,256,0,stream>>>(x1p, KSO, (long long)2048*1024, n2w, x1, h2b, h2f);
  router_kernel<<<2048,256,0,stream>>>(h2f, rw, probs, tope, topw, counts);
  prefix_kernel<<<1,64,0,stream>>>(counts, offs);
  scatter_kernel<<<8,256,0,stream>>>(tope, topw, offs, cursor, tok_list, wgt);
  // w1 weights -> bf16, then w1 GEMM: per-expert M<=2048 N=4096 K=1024 -> grid (32,16,8)
  conv_kernel<<<16384,256,0,stream>>>(w1, wb, 32*1024*1024/8);
  gemm_bb<2,true><<<dim3(32,16,8),256,0,stream>>>(h2b,1024, wb,(long long)4096*1024,1024, 2048,4096,1024, 1,0,
      counts,offs,tok_list,nullptr,nullptr, nullptr,hid,4096);
  // w2 weights -> bf16, then w2 GEMM: per-expert M<=2048 N=1024 K=4096 split KSW -> grid (8,16,16)
  conv_kernel<<<16384,256,0,stream>>>(w2, wb, 32*1024*1024/8);
  gemm_bb<3,false><<<dim3(8,16,8*KSW),256,0,stream>>>(hid,4096, wb,(long long)4096*1024,4096, 2048,1024,4096, KSW,(long long)4096*1024,
      counts,offs,tok_list,wgt,nullptr, slots,nullptr,1024);
  aux_kernel<<<1,256,0,stream>>>(probs, out);
  final_kernel<<<2048,256,0,stream>>>(x1, slots, KSW, (long long)4096*1024, out);
}

// Round 12
// 406.057 us; speedup vs baseline: 2.1367x; 1.0320x over previous
//
#include <hip/hip_runtime.h>
#include <cstdint>
#include <math.h>

typedef float f32x4 __attribute__((ext_vector_type(4)));
typedef __bf16 bf16x8 __attribute__((ext_vector_type(8)));
typedef unsigned short us4 __attribute__((ext_vector_type(4)));
typedef unsigned short us8 __attribute__((ext_vector_type(8)));

#define DEV static __device__ __forceinline__

DEV unsigned short f2bf(float f){
  union { __bf16 h; unsigned short u; } cv; cv.h = (__bf16)f; return cv.u;
}
DEV float bf2f(unsigned short u){ return __uint_as_float((unsigned int)u << 16); }

DEV void gload16(const void* g, void* l){
  __builtin_amdgcn_global_load_lds((__attribute__((address_space(1))) void*)g,
                                   (__attribute__((address_space(3))) void*)l, 16, 0, 0);
}

// ---------------- fp32 -> bf16 weight conversion (streaming) ----------------
__global__ __launch_bounds__(256) void conv_kernel(const float* __restrict__ src,
    unsigned short* __restrict__ dst, int n8){
  int i = blockIdx.x*256 + threadIdx.x;
  if (i >= n8) return;
  float4 a = ((const float4*)src)[2*i];
  float4 b = ((const float4*)src)[2*i+1];
  us8 o = { f2bf(a.x), f2bf(a.y), f2bf(a.z), f2bf(a.w),
            f2bf(b.x), f2bf(b.y), f2bf(b.z), f2bf(b.w) };
  ((us8*)dst)[i] = o;
}

// ---------------- V transpose: qkvb V part [t][h*64+d] -> vt[h][d][t] ----------------
__global__ __launch_bounds__(256) void vtrans_kernel(const unsigned short* __restrict__ qkvb,
    unsigned short* __restrict__ vt){
  int tt = blockIdx.x, h = blockIdx.y;
  int t0 = tt*64;
  __shared__ unsigned short tile[64][72];
  int r = threadIdx.x >> 2, cb = (threadIdx.x & 3) * 16;
  const unsigned short* src = qkvb + (long long)(t0+r)*3072 + 2048 + h*64 + cb;
  us8 a = *(const us8*)src;
  us8 b = *(const us8*)(src+8);
  #pragma unroll
  for (int i=0;i<8;++i){ tile[r][cb+i] = a[i]; tile[r][cb+8+i] = b[i]; }
  __syncthreads();
  unsigned short o[16];
  #pragma unroll
  for (int i=0;i<16;++i) o[i] = tile[cb+i][r];
  unsigned short* dst = vt + (long long)(h*64+r)*2048 + t0 + cb;
  *(us8*)dst = *(us8*)&o[0];
  *(us8*)(dst+8) = *(us8*)&o[8];
}

// ---------------- RMSNorm 1 ----------------
__global__ __launch_bounds__(256) void rmsnorm_kernel(const float* __restrict__ x, const float* __restrict__ w,
    unsigned short* __restrict__ ob){
  int t = blockIdx.x, tid = threadIdx.x;
  float4 xv = *(const float4*)(x + (long long)t*1024 + tid*4);
  float ss = xv.x*xv.x + xv.y*xv.y + xv.z*xv.z + xv.w*xv.w;
  for (int m=32;m;m>>=1) ss += __shfl_xor(ss,m);
  __shared__ float lds[4];
  if ((tid&63)==0) lds[tid>>6] = ss;
  __syncthreads();
  float tot = lds[0]+lds[1]+lds[2]+lds[3];
  float inv = rsqrtf(tot*(1.0f/1024.0f) + 1.1920928955078125e-07f);
  float4 wv = *(const float4*)(w + tid*4);
  us4 rb = { f2bf(xv.x*inv*wv.x), f2bf(xv.y*inv*wv.y), f2bf(xv.z*inv*wv.z), f2bf(xv.w*inv*wv.w) };
  *(us4*)&ob[(long long)t*1024 + tid*4] = rb;
}

// ---------------- RMSNorm 2 ----------------
__global__ __launch_bounds__(256) void rmsnorm2_kernel(const float* __restrict__ xp, int ksn, long long kstride,
    const float* __restrict__ w, float* __restrict__ x1, unsigned short* __restrict__ hb, float* __restrict__ hf){
  int t = blockIdx.x, tid = threadIdx.x;
  long long b = (long long)t*1024 + tid*4;
  float4 xv = {0.f,0.f,0.f,0.f};
  for (int ks=0; ks<ksn; ++ks){
    float4 a = *(const float4*)(xp + ks*kstride + b);
    xv.x+=a.x; xv.y+=a.y; xv.z+=a.z; xv.w+=a.w;
  }
  *(float4*)(x1 + b) = xv;
  float ss = xv.x*xv.x + xv.y*xv.y + xv.z*xv.z + xv.w*xv.w;
  for (int m=32;m;m>>=1) ss += __shfl_xor(ss,m);
  __shared__ float lds[4];
  if ((tid&63)==0) lds[tid>>6] = ss;
  __syncthreads();
  float tot = lds[0]+lds[1]+lds[2]+lds[3];
  float inv = rsqrtf(tot*(1.0f/1024.0f) + 1.1920928955078125e-07f);
  float4 wv = *(const float4*)(w + tid*4);
  float r0 = xv.x*inv*wv.x, r1 = xv.y*inv*wv.y, r2 = xv.z*inv*wv.z, r3 = xv.w*inv*wv.w;
  us4 rb = { f2bf(r0), f2bf(r1), f2bf(r2), f2bf(r3) };
  *(us4*)&hb[b] = rb;
  float4 rf; rf.x=r0; rf.y=r1; rf.z=r2; rf.w=r3;
  *(float4*)(hf + b) = rf;
}

// ---------------- m97-replica GEMM  C[M,N] = A[M,K](bf16) * B[N,K]^T(bf16) ----------------
// BM=128, BN in {128,64}. 256 thr, 4 waves: BN=128 -> 2x2 waves (64x64 each);
// BN=64 -> 4x1 waves (32x64 each). BK=64, single-buffered LDS, global_load_lds
// both operands with pre-swizzled source c^(R&7); 2-barrier loop (m97/m114).
// EPI: 1 = fp32 (+resid if ks==0), 2 = gelu->bf16 rows rbase+lr, 3 = *wgt scatter, 4 = bf16
template<int EPI, bool GATHER, int BN>
__global__ __launch_bounds__(256) void gemm_bb(
    const unsigned short* __restrict__ A, int lda,
    const unsigned short* __restrict__ Bb, long long bstride, int ldb,
    int M, int N, int K, int KS, long long ksoff,
    const int* __restrict__ counts, const int* __restrict__ offs,
    const int* __restrict__ tok_list, const float* __restrict__ wgt,
    const float* __restrict__ resid,
    float* __restrict__ Cf, unsigned short* __restrict__ Cb, int ldc)
{
  constexpr int MF = (BN==128) ? 4 : 2;       // m-frags per wave
  constexpr int BLOADS = BN/32;               // B gload16 per thread
  const int z = blockIdx.z;
  const int e = z / KS, ks = z - e*KS;
  const int Me = counts ? counts[e] : M;
  const int by = blockIdx.y;
  if (by * 128 >= Me) return;
  const int rbase = offs ? offs[e] : 0;
  const int bx = blockIdx.x;
  const unsigned short* B = Bb + (long long)e * bstride;
  const int kn = K / KS;
  const int kbeg = ks * kn;

  __shared__ __align__(16) unsigned short As[128*64];
  __shared__ __align__(16) unsigned short Bs[BN*64];

  const int tid = threadIdx.x, lane = tid & 63, w = tid >> 6;
  const int wr = (BN==128) ? (w >> 1) : w;
  const int wc = (BN==128) ? (w & 1) : 0;
  const int l15 = lane & 15, l4 = lane >> 4;

  const unsigned short* asrc[4];
  #pragma unroll
  for (int j=0;j<4;++j){
    int G = j*256 + tid;
    int R = G >> 3, c = G & 7;
    int sc = c ^ (R & 7);
    int lr = by*128 + R; if (lr >= Me) lr = Me-1;
    int li = rbase + lr;
    int ar = GATHER ? (tok_list[li] >> 1) : li;
    asrc[j] = A + (long long)ar*lda + kbeg + sc*8;
  }
  const unsigned short* bsrc[BLOADS];
  #pragma unroll
  for (int j=0;j<BLOADS;++j){
    int G = j*256 + tid;
    int R = G >> 3, c = G & 7;
    int sc = c ^ (R & 7);
    bsrc[j] = B + (long long)(bx*BN + R)*ldb + kbeg + sc*8;
  }

  f32x4 acc[MF][4] = {};

  for (int k0 = 0; k0 < kn; k0 += 64){
    __syncthreads();
    #pragma unroll
    for (int j=0;j<4;++j) gload16(asrc[j] + k0, &As[(j*256+tid)*8]);
    #pragma unroll
    for (int j=0;j<BLOADS;++j) gload16(bsrc[j] + k0, &Bs[(j*256+tid)*8]);
    __syncthreads();
    #pragma unroll
    for (int kk=0;kk<2;++kk){
      bf16x8 af[MF], bfr[4];
      #pragma unroll
      for (int m=0;m<MF;++m){
        int R = wr*(MF*16) + m*16 + l15;
        int c = (l4 + 4*kk) ^ (R&7);
        af[m] = *(const bf16x8*)&As[R*64 + c*8];
      }
      #pragma unroll
      for (int n=0;n<4;++n){
        int R = wc*64 + n*16 + l15;
        int c = (l4 + 4*kk) ^ (R&7);
        bfr[n] = *(const bf16x8*)&Bs[R*64 + c*8];
      }
      #pragma unroll
      for (int m=0;m<MF;++m)
        #pragma unroll
        for (int n=0;n<4;++n)
          acc[m][n] = __builtin_amdgcn_mfma_f32_16x16x32_bf16(af[m], bfr[n], acc[m][n], 0, 0, 0);
    }
  }

  #pragma unroll
  for (int m=0;m<MF;++m){
    #pragma unroll
    for (int r2=0;r2<4;++r2){
      int lr = by*128 + wr*(MF*16) + m*16 + 4*l4 + r2;
      if (lr >= Me) continue;
      #pragma unroll
      for (int n=0;n<4;++n){
        int col = bx*BN + wc*64 + n*16 + l15;
        float v = acc[m][n][r2];
        if constexpr (EPI == 1){
          if (ks == 0) v += resid[(long long)lr*ldc + col];
          Cf[ks*ksoff + (long long)lr*ldc + col] = v;
        } else if constexpr (EPI == 2){
          float g = 0.5f * v * (1.0f + erff(v * 0.70710678118654752f));
          Cb[(long long)(rbase+lr)*ldc + col] = f2bf(g);
        } else if constexpr (EPI == 3){
          int gi = rbase + lr;
          int ts = tok_list[gi];
          Cf[ks*ksoff + (long long)ts*ldc + col] = v * wgt[gi];
        } else {
          Cb[(long long)lr*ldc + col] = f2bf(v);
        }
      }
    }
  }
}

// ---------------- RoPE ----------------
__global__ __launch_bounds__(256) void rope_kernel(const unsigned short* __restrict__ qkvb,
    unsigned short* __restrict__ q, unsigned short* __restrict__ k){
  int t = blockIdx.x, tid = threadIdx.x;
  const unsigned short* row = qkvb + (long long)t*3072;
  #pragma unroll
  for (int u2=0; u2<2; ++u2){
    int pid = tid + u2*256;
    int hh = pid >> 5, j = pid & 31;
    float invf = __expf(-(float)j * 0.28782313662425575f);
    float fr = (float)t * invf;
    float sn, cs;
    __sincosf(fr, &sn, &cs);
    int base = hh*64 + j;
    long long ob_ = (long long)t*1024 + base;
    float a = bf2f(row[base]), b = bf2f(row[base+32]);
    q[ob_]    = f2bf(a*cs - b*sn);
    q[ob_+32] = f2bf(b*cs + a*sn);
    a = bf2f(row[1024+base]); b = bf2f(row[1024+base+32]);
    k[ob_]    = f2bf(a*cs - b*sn);
    k[ob_+32] = f2bf(b*cs + a*sn);
  }
}

// ---------------- causal flash attention (V^T in vt[h][d][t]) ----------------
__global__ __launch_bounds__(256) void attn_kernel(
    const unsigned short* __restrict__ Q,
    const unsigned short* __restrict__ K,
    const unsigned short* __restrict__ Vt,
    unsigned short* __restrict__ O)
{
  const int bx = gridDim.x - 1 - blockIdx.x;   // longest blocks dispatch first
  const int h = blockIdx.y;
  const int q0 = bx*64;
  const int tid = threadIdx.x, lane = tid&63, w = tid>>6;
  const int l15 = lane & 15, l4 = lane >> 4;

  __shared__ __align__(16) unsigned short Ks[64*64];
  __shared__ __align__(16) unsigned short Vs[64*64];
  __shared__ __align__(16) unsigned short Ps[4*16*64];
  unsigned short* Pw = Ps + w*1024;

  const int qrow = q0 + w*16 + l15;
  bf16x8 aq[2];
  #pragma unroll
  for (int kk=0;kk<2;++kk)
    aq[kk] = *(const bf16x8*)&Q[(long long)qrow*1024 + h*64 + 32*kk + 8*l4];

  f32x4 o[4] = {};
  float Mx[4] = {-INFINITY,-INFINITY,-INFINITY,-INFINITY};
  float Ls[4] = {0.f,0.f,0.f,0.f};

  const int row_g = q0 + w*16 + 4*l4;
  const int nt = bx + 1;
  for (int it = 0; it < nt; ++it){
    int k0 = it*64;
    #pragma unroll
    for (int i=0;i<2;++i){
      int seg = 4*i + w;
      int row = seg*8 + (lane>>3);
      int cs = (lane&7) ^ (row&7);
      gload16(&K[(long long)(k0+row)*1024 + h*64 + cs*8], &Ks[seg*512]);
      gload16(&Vt[(long long)(h*64+row)*2048 + k0 + cs*8], &Vs[seg*512]);
    }
    __syncthreads();
    f32x4 st[4];
    #pragma unroll
    for (int kt=0;kt<4;++kt){
      f32x4 s = {0.f,0.f,0.f,0.f};
      #pragma unroll
      for (int kk=0;kk<2;++kk){
        int R = kt*16 + l15;
        int ch = (l4+4*kk) ^ (R&7);
        bf16x8 bk = *(const bf16x8*)&Ks[R*64 + ch*8];
        s = __builtin_amdgcn_mfma_f32_16x16x32_bf16(aq[kk], bk, s, 0,0,0);
      }
      st[kt] = s;
    }
    #pragma unroll
    for (int kt=0;kt<4;++kt){
      int col = k0 + kt*16 + l15;
      #pragma unroll
      for (int r=0;r<4;++r){
        float vv = st[kt][r]*0.125f;
        st[kt][r] = (col <= row_g + r) ? vv : -INFINITY;
      }
    }
    float sf[4];
    #pragma unroll
    for (int r=0;r<4;++r){
      float mx = fmaxf(fmaxf(st[0][r],st[1][r]),fmaxf(st[2][r],st[3][r]));
      mx = fmaxf(mx, __shfl_xor(mx,1));
      mx = fmaxf(mx, __shfl_xor(mx,2));
      mx = fmaxf(mx, __shfl_xor(mx,4));
      mx = fmaxf(mx, __shfl_xor(mx,8));
      float mn = fmaxf(Mx[r], mx);
      float sc = __expf(Mx[r]-mn);
      Mx[r]=mn; sf[r]=sc;
      float ls=0.f;
      #pragma unroll
      for (int kt=0;kt<4;++kt){ float pp = __expf(st[kt][r]-mn); st[kt][r]=pp; ls+=pp; }
      Ls[r] = Ls[r]*sc + ls;
    }
    #pragma unroll
    for (int dt=0;dt<4;++dt)
      #pragma unroll
      for (int r=0;r<4;++r) o[dt][r] *= sf[r];
    #pragma unroll
    for (int kt=0;kt<4;++kt)
      #pragma unroll
      for (int r=0;r<4;++r){
        int prow = 4*l4+r, pcol = kt*16+l15;
        int byteoff = (prow*128 + pcol*2) ^ ((prow&7)<<4);
        *(unsigned short*)((char*)Pw + byteoff) = f2bf(st[kt][r]);
      }
    bf16x8 pa[2];
    #pragma unroll
    for (int kk=0;kk<2;++kk){
      int pr = l15;
      int ch = (l4+4*kk) ^ (pr&7);
      pa[kk] = *(const bf16x8*)&Pw[pr*64 + ch*8];
    }
    #pragma unroll
    for (int dt=0;dt<4;++dt){
      #pragma unroll
      for (int kk=0;kk<2;++kk){
        int R = dt*16 + l15;
        int c = (l4 + 4*kk) ^ (R&7);
        bf16x8 bv = *(const bf16x8*)&Vs[R*64 + c*8];
        o[dt] = __builtin_amdgcn_mfma_f32_16x16x32_bf16(pa[kk], bv, o[dt], 0,0,0);
      }
    }
    __syncthreads();
  }
  #pragma unroll
  for (int r=0;r<4;++r){
    float l = Ls[r];
    l += __shfl_xor(l,1); l += __shfl_xor(l,2); l += __shfl_xor(l,4); l += __shfl_xor(l,8);
    Ls[r] = 1.0f / l;
  }
  #pragma unroll
  for (int dt=0;dt<4;++dt)
    #pragma unroll
    for (int r=0;r<4;++r){
      float vv = o[dt][r]*Ls[r];
      int rg = row_g + r;
      O[(long long)rg*1024 + h*64 + dt*16 + l15] = f2bf(vv);
    }
}

// ---------------- router + top2 ----------------
__global__ __launch_bounds__(256) void router_kernel(const float* __restrict__ h2f, const float* __restrict__ rw,
    float* __restrict__ probs, int* __restrict__ tope, float* __restrict__ topw, int* __restrict__ counts){
  int t = blockIdx.x, tid = threadIdx.x;
  float4 hv = *(const float4*)(h2f + (long long)t*1024 + tid*4);
  float pe[8];
  #pragma unroll
  for (int e2=0;e2<8;++e2){
    float4 wv = *(const float4*)(rw + e2*1024 + tid*4);
    pe[e2] = hv.x*wv.x + hv.y*wv.y + hv.z*wv.z + hv.w*wv.w;
  }
  __shared__ float lds[32];
  #pragma unroll
  for (int e2=0;e2<8;++e2){
    float v = pe[e2];
    for (int m=32;m;m>>=1) v += __shfl_xor(v,m);
    if ((tid&63)==0) lds[(tid>>6)*8+e2] = v;
  }
  __syncthreads();
  if (tid==0){
    float lg[8], pp[8];
    #pragma unroll
    for (int e2=0;e2<8;++e2) lg[e2] = lds[e2]+lds[8+e2]+lds[16+e2]+lds[24+e2];
    float mx = lg[0];
    for (int e2=1;e2<8;++e2) mx = fmaxf(mx, lg[e2]);
    float s = 0.f;
    for (int e2=0;e2<8;++e2){ pp[e2] = __expf(lg[e2]-mx); s += pp[e2]; }
    float inv = 1.0f/s;
    int i0 = 0;
    for (int e2=1;e2<8;++e2) if (pp[e2] > pp[i0]) i0 = e2;
    int i1 = (i0==0)?1:0;
    for (int e2=0;e2<8;++e2) if (e2!=i0 && pp[e2] > pp[i1]) i1 = e2;
    for (int e2=0;e2<8;++e2) probs[t*8+e2] = pp[e2]*inv;
    float p0 = pp[i0], p1 = pp[i1], wsum = p0+p1;
    tope[t*2] = i0; tope[t*2+1] = i1;
    topw[t*2] = p0/wsum; topw[t*2+1] = p1/wsum;
    atomicAdd(&counts[i0],1); atomicAdd(&counts[i1],1);
  }
}

__global__ void init_kernel(int* counts, int* cursor){
  int i = threadIdx.x;
  if (i<8){ counts[i]=0; cursor[i]=0; }
}

__global__ void prefix_kernel(const int* counts, int* offs){
  if (threadIdx.x==0){
    int a=0;
    for (int e2=0;e2<8;++e2){ offs[e2]=a; a+=counts[e2]; }
  }
}

__global__ void scatter_kernel(const int* __restrict__ tope, const float* __restrict__ topw,
    const int* __restrict__ offs, int* __restrict__ cursor, int* __restrict__ tok_list, float* __restrict__ wgt){
  int t = blockIdx.x*blockDim.x + threadIdx.x;
  if (t >= 2048) return;
  #pragma unroll
  for (int s=0;s<2;++s){
    int e2 = tope[t*2+s];
    int pos = atomicAdd(&cursor[e2], 1);
    int i = offs[e2] + pos;
    tok_list[i] = t*2+s;
    wgt[i] = topw[t*2+s];
  }
}

__global__ __launch_bounds__(256) void aux_kernel(const float* __restrict__ probs, float* __restrict__ out){
  int tid = threadIdx.x;
  float pe[8] = {0,0,0,0,0,0,0,0};
  for (int t = tid; t < 2048; t += 256){
    #pragma unroll
    for (int e2=0;e2<8;++e2) pe[e2] += probs[t*8+e2];
  }
  __shared__ float lds[32];
  #pragma unroll
  for (int e2=0;e2<8;++e2){
    float v = pe[e2];
    for (int m=32;m;m>>=1) v += __shfl_xor(v,m);
    if ((tid&63)==0) lds[(tid>>6)*8 + e2] = v;
  }
  __syncthreads();
  if (tid==0){
    float aux = 0.f;
    #pragma unroll
    for (int e2=0;e2<8;++e2){
      float mean = (lds[e2]+lds[8+e2]+lds[16+e2]+lds[24+e2]) * (1.0f/2048.0f);
      aux += mean*mean;
    }
    out[2097152] = 8.0f * aux;
  }
}

__global__ __launch_bounds__(256) void final_kernel(const float* __restrict__ x1, const float* __restrict__ slots,
    int ksn, long long kstride, float* __restrict__ out){
  int t = blockIdx.x, tid = threadIdx.x;
  long long b = (long long)t*1024 + tid*4;
  float4 a = *(const float4*)(x1 + b);
  long long s = (long long)t*2048 + tid*4;
  for (int ks=0; ks<ksn; ++ks){
    float4 s0 = *(const float4*)(slots + ks*kstride + s);
    float4 s1 = *(const float4*)(slots + ks*kstride + s + 1024);
    a.x += s0.x + s1.x; a.y += s0.y + s1.y; a.z += s0.z + s1.z; a.w += s0.w + s1.w;
  }
  *(float4*)(out + b) = a;
}

extern "C" void kernel_launch(void* const* d_in, const int* in_sizes, int n_in,
                              void* d_out, int out_size, void* d_ws, size_t ws_size,
                              hipStream_t stream)
{
  (void)in_sizes; (void)n_in; (void)out_size; (void)ws_size;
  const float* x    = (const float*)d_in[0];
  const float* qkvw = (const float*)d_in[1];
  const float* outw = (const float*)d_in[2];
  const float* rw   = (const float*)d_in[3];
  const float* w1   = (const float*)d_in[4];
  const float* w2   = (const float*)d_in[5];
  const float* n1w  = (const float*)d_in[6];
  const float* n2w  = (const float*)d_in[7];
  float* out = (float*)d_out;

  char* base = (char*)d_ws;
  const size_t MB = 1ull<<20;
  const int KSO = 2;   // out-proj split-K
  const int KSW = 2;   // w2 split-K

  // [0,32MB): pre-MoE bf16 activation buffers; hid aliases whole region after attn phase
  unsigned short* h_b  = (unsigned short*)(base + 0*MB);
  unsigned short* qb   = (unsigned short*)(base + 4*MB);
  unsigned short* kb   = (unsigned short*)(base + 8*MB);
  unsigned short* ob   = (unsigned short*)(base + 12*MB);
  unsigned short* qkvb = (unsigned short*)(base + 16*MB);   // 12MB
  unsigned short* vt   = (unsigned short*)(base + 28*MB);   // 4MB
  unsigned short* hid  = (unsigned short*)(base + 0*MB);    // 32MB alias

  // [32,96MB): bf16 weight region (reused serially): wbq+wbo early, then w1, then w2
  unsigned short* wbq = (unsigned short*)(base + 32*MB);    // 6MB
  unsigned short* wbo = (unsigned short*)(base + 40*MB);    // 2MB
  unsigned short* wb  = (unsigned short*)(base + 32*MB);    // 64MB (w1 then w2)

  // [96,128): out-proj fp32 partials (KSO x 8MB); slots aliases after rmsnorm2
  float* x1p   = (float*)(base + 96*MB);
  float* slots = (float*)(base + 96*MB);    // KSW x 16MB
  float* h2f   = (float*)(base + 128*MB);   // 8MB
  float* x1    = (float*)(base + 136*MB);   // 8MB
  unsigned short* h2b = (unsigned short*)(base + 144*MB);   // 4MB
  char* small_ = base + 148*MB;

  float* probs = (float*)(small_);
  int*   tope  = (int*)(small_ + 256*1024);
  float* topw  = (float*)(small_ + 512*1024);
  int*   tok_list = (int*)(small_ + 768*1024);
  float* wgt   = (float*)(small_ + 1024*1024);
  int*   counts= (int*)(small_ + 1536*1024);
  int*   offs  = (int*)(small_ + 1536*1024 + 256);
  int*   cursor= (int*)(small_ + 1536*1024 + 512);

  init_kernel<<<1,64,0,stream>>>(counts, cursor);
  rmsnorm_kernel<<<2048,256,0,stream>>>(x, n1w, h_b);
  conv_kernel<<<1536,256,0,stream>>>(qkvw, wbq, 3*1024*1024/8);
  conv_kernel<<<512,256,0,stream>>>(outw, wbo, 1024*1024/8);
  // qkv: M=2048 N=3072 K=1024, BN=64 -> grid (48,16) = 768 blocks
  gemm_bb<4,false,64><<<dim3(48,16,1),256,0,stream>>>(h_b,1024, wbq,0,1024, 2048,3072,1024, 1,0,
      nullptr,nullptr,nullptr,nullptr,nullptr, nullptr,qkvb,3072);
  rope_kernel<<<2048,256,0,stream>>>(qkvb, qb, kb);
  vtrans_kernel<<<dim3(32,16),256,0,stream>>>(qkvb, vt);
  attn_kernel<<<dim3(32,16),256,0,stream>>>(qb, kb, vt, ob);
  // out-proj: M=2048 N=1024 K=1024, BN=64, split KSO=2 -> grid (16,16,2) = 512 blocks, 8 K-iters
  gemm_bb<1,false,64><<<dim3(16,16,KSO),256,0,stream>>>(ob,1024, wbo,0,1024, 2048,1024,1024, KSO,(long long)2048*1024,
      nullptr,nullptr,nullptr,nullptr, x, x1p,nullptr,1024);
  rmsnorm2_kernel<<<2048,256,0,stream>>>(x1p, KSO, (long long)2048*1024, n2w, x1, h2b, h2f);
  router_kernel<<<2048,256,0,stream>>>(h2f, rw, probs, tope, topw, counts);
  prefix_kernel<<<1,64,0,stream>>>(counts, offs);
  scatter_kernel<<<8,256,0,stream>>>(tope, topw, offs, cursor, tok_list, wgt);
  // w1 weights -> bf16, then w1 GEMM: per-expert M<=2048 N=4096 K=1024 -> grid (32,16,8)
  conv_kernel<<<16384,256,0,stream>>>(w1, wb, 32*1024*1024/8);
  gemm_bb<2,true,128><<<dim3(32,16,8),256,0,stream>>>(h2b,1024, wb,(long long)4096*1024,1024, 2048,4096,1024, 1,0,
      counts,offs,tok_list,nullptr,nullptr, nullptr,hid,4096);
  // w2 weights -> bf16, then w2 GEMM: per-expert M<=2048 N=1024 K=4096 split KSW -> grid (8,16,16)
  conv_kernel<<<16384,256,0,stream>>>(w2, wb, 32*1024*1024/8);
  gemm_bb<3,false,128><<<dim3(8,16,8*KSW),256,0,stream>>>(hid,4096, wb,(long long)4096*1024,4096, 2048,1024,4096, KSW,(long long)4096*1024,
      counts,offs,tok_list,wgt,nullptr, slots,nullptr,1024);
  aux_kernel<<<1,256,0,stream>>>(probs, out);
  final_kernel<<<2048,256,0,stream>>>(x1, slots, KSW, (long long)4096*1024, out);
}